// Round 1
// baseline (9946.485 us; speedup 1.0000x reference)
//
#include <hip/hip_runtime.h>
#include <hip/hip_bf16.h>
#include <cstddef>

// ---------------------------------------------------------------------------
// Transformer encoder-decoder forward (fp32 baseline).
// D=512, NH=8 (dk=64), FF=2048, LE=LD=6, V=97, SM=512, SQ=128, B=16.
// All matmuls are X @ W^T (+bias)  => NT GEMM with K contiguous in both.
// ---------------------------------------------------------------------------

#define D_MODEL 512
#define N_HEADS 8
#define DK 64
#define BATCH 16
#define EPS_LN 1e-5f

__device__ __forceinline__ float dot4(float4 a, float4 b) {
    return a.x * b.x + a.y * b.y + a.z * b.z + a.w * b.w;
}

// ---------------------------------------------------------------------------
// GEMM: C[N,M] = act(A[N,K] @ W[M,K]^T + bias[M])
// BM=BN=64, BK=32, 256 threads, 4x4 per thread. N%64==0, K%32==0 guaranteed.
// M bounds-checked (final gemm has M=97).
// ---------------------------------------------------------------------------
__global__ __launch_bounds__(256) void gemm_nt(
    const float* __restrict__ A, const float* __restrict__ W,
    const float* __restrict__ bias, float* __restrict__ C,
    int N, int M, int K, int relu)
{
    constexpr int BK = 32;
    __shared__ __align__(16) float As[BK][68];
    __shared__ __align__(16) float Ws[BK][68];

    const int tid  = threadIdx.x;
    const int row0 = blockIdx.y * 64;
    const int col0 = blockIdx.x * 64;
    const int tx = tid & 15;        // col group
    const int ty = tid >> 4;        // row group
    const int lr  = tid >> 2;       // 0..63 load row
    const int kq0 = (tid & 3) * 2;  // float4 index base (0,2,4,6)

    float acc[4][4];
#pragma unroll
    for (int i = 0; i < 4; ++i)
#pragma unroll
        for (int j = 0; j < 4; ++j) acc[i][j] = 0.f;

    for (int kt = 0; kt < K; kt += BK) {
        // Stage A tile [64 rows][32 k]
#pragma unroll
        for (int h = 0; h < 2; ++h) {
            int kq = kq0 + h;
            float4 v = *(const float4*)(A + (size_t)(row0 + lr) * K + kt + kq * 4);
            As[kq * 4 + 0][lr] = v.x; As[kq * 4 + 1][lr] = v.y;
            As[kq * 4 + 2][lr] = v.z; As[kq * 4 + 3][lr] = v.w;
        }
        // Stage W tile [64 out-cols][32 k]
#pragma unroll
        for (int h = 0; h < 2; ++h) {
            int kq = kq0 + h;
            int wr = col0 + lr;
            float4 v = make_float4(0.f, 0.f, 0.f, 0.f);
            if (wr < M) v = *(const float4*)(W + (size_t)wr * K + kt + kq * 4);
            Ws[kq * 4 + 0][lr] = v.x; Ws[kq * 4 + 1][lr] = v.y;
            Ws[kq * 4 + 2][lr] = v.z; Ws[kq * 4 + 3][lr] = v.w;
        }
        __syncthreads();
#pragma unroll
        for (int k = 0; k < BK; ++k) {
            float4 a4 = *(const float4*)&As[k][ty * 4];   // rows ty*4..+3 (broadcast)
            float4 b4 = *(const float4*)&Ws[k][tx * 4];   // cols tx*4..+3
            float ar[4] = {a4.x, a4.y, a4.z, a4.w};
            float br[4] = {b4.x, b4.y, b4.z, b4.w};
#pragma unroll
            for (int i = 0; i < 4; ++i)
#pragma unroll
                for (int j = 0; j < 4; ++j) acc[i][j] += ar[i] * br[j];
        }
        __syncthreads();
    }

    // Epilogue
    if ((M & 63) == 0) {
        // fully vectorizable path
        const int c0 = col0 + tx * 4;
        float4 bv = *(const float4*)(bias + c0);
#pragma unroll
        for (int i = 0; i < 4; ++i) {
            int rr = row0 + ty * 4 + i;
            float4 o;
            o.x = acc[i][0] + bv.x; o.y = acc[i][1] + bv.y;
            o.z = acc[i][2] + bv.z; o.w = acc[i][3] + bv.w;
            if (relu) {
                o.x = fmaxf(o.x, 0.f); o.y = fmaxf(o.y, 0.f);
                o.z = fmaxf(o.z, 0.f); o.w = fmaxf(o.w, 0.f);
            }
            *(float4*)(C + (size_t)rr * M + c0) = o;
        }
    } else {
#pragma unroll
        for (int i = 0; i < 4; ++i) {
            int rr = row0 + ty * 4 + i;
#pragma unroll
            for (int j = 0; j < 4; ++j) {
                int c = col0 + tx * 4 + j;
                if (c < M) {
                    float v = acc[i][j] + bias[c];
                    if (relu) v = fmaxf(v, 0.f);
                    C[(size_t)rr * M + c] = v;
                }
            }
        }
    }
}

// ---------------------------------------------------------------------------
// Flash-style attention. Token layout: row (s*BATCH + b), head offset h*64.
// Block: 256 threads = 64 q-rows x 4 dim-quarters. KV staged in 64-key LDS
// chunks with online softmax. Output written to O[(s*B+b)*512 + h*64 + d].
// grid = (Sq/64, NH, BATCH)
// ---------------------------------------------------------------------------
template <int CAUSAL>
__global__ __launch_bounds__(256) void attn_kern(
    const float* __restrict__ Qp, const float* __restrict__ Kp,
    const float* __restrict__ Vp, float* __restrict__ Op,
    int Skv, int qstride, int kvstride, float scale)
{
    constexpr int KB = 64;
    __shared__ __align__(16) float Ks[KB][68];
    __shared__ __align__(16) float Vs[KB][68];

    const int tid = threadIdx.x;
    const int q0  = blockIdx.x * 64;
    const int h   = blockIdx.y;
    const int b   = blockIdx.z;
    const int r   = tid >> 2;   // local q row
    const int qd  = tid & 3;    // dim quarter
    const int sq  = q0 + r;

    // q row quarter -> registers (pre-scaled)
    float4 q4[4];
    const float* qrow = Qp + ((size_t)sq * BATCH + b) * qstride + h * DK + qd * 16;
#pragma unroll
    for (int i = 0; i < 4; ++i) {
        q4[i] = *(const float4*)(qrow + i * 4);
        q4[i].x *= scale; q4[i].y *= scale; q4[i].z *= scale; q4[i].w *= scale;
    }

    float4 acc[4];
#pragma unroll
    for (int i = 0; i < 4; ++i) acc[i] = make_float4(0.f, 0.f, 0.f, 0.f);
    float m = -1e30f, l = 0.f;

    const int nkc = CAUSAL ? (q0 / KB + 1) : (Skv / KB);
    for (int kc = 0; kc < nkc; ++kc) {
        // Stage K and V chunk (64 keys x 64 dims each)
        {
            const int kr = tid >> 2, part = tid & 3;
            const size_t tok = ((size_t)(kc * KB + kr) * BATCH + b) * kvstride + h * DK + part * 16;
#pragma unroll
            for (int i = 0; i < 4; ++i) {
                *(float4*)&Ks[kr][part * 16 + i * 4] = *(const float4*)(Kp + tok + i * 4);
                *(float4*)&Vs[kr][part * 16 + i * 4] = *(const float4*)(Vp + tok + i * 4);
            }
        }
        __syncthreads();

        // Partial scores over this lane's 16 dims, all 64 keys
        float ps[KB];
#pragma unroll
        for (int key = 0; key < KB; ++key) {
            float4 k0 = *(const float4*)&Ks[key][qd * 16 + 0];
            float4 k1 = *(const float4*)&Ks[key][qd * 16 + 4];
            float4 k2 = *(const float4*)&Ks[key][qd * 16 + 8];
            float4 k3 = *(const float4*)&Ks[key][qd * 16 + 12];
            ps[key] = dot4(q4[0], k0) + dot4(q4[1], k1) + dot4(q4[2], k2) + dot4(q4[3], k3);
        }
        // Reduce across the 4 quarter-lanes -> full score in all 4 lanes
#pragma unroll
        for (int key = 0; key < KB; ++key) {
            ps[key] += __shfl_xor(ps[key], 1, 4);
            ps[key] += __shfl_xor(ps[key], 2, 4);
            if (CAUSAL) {
                if (kc * KB + key > sq) ps[key] = -1e30f;
            }
        }
        // Online softmax
        float cmax = ps[0];
#pragma unroll
        for (int key = 1; key < KB; ++key) cmax = fmaxf(cmax, ps[key]);
        float mn   = fmaxf(m, cmax);
        float corr = __expf(m - mn);
        l *= corr;
#pragma unroll
        for (int i = 0; i < 4; ++i) {
            acc[i].x *= corr; acc[i].y *= corr; acc[i].z *= corr; acc[i].w *= corr;
        }
        float lsum = 0.f;
#pragma unroll
        for (int key = 0; key < KB; ++key) {
            float p = __expf(ps[key] - mn);
            ps[key] = p;
            lsum += p;
        }
        l += lsum;
        m = mn;
        // PV accumulate (this lane's 16 dims)
#pragma unroll
        for (int key = 0; key < KB; ++key) {
            float p = ps[key];
#pragma unroll
            for (int i = 0; i < 4; ++i) {
                float4 v4 = *(const float4*)&Vs[key][qd * 16 + i * 4];
                acc[i].x += p * v4.x; acc[i].y += p * v4.y;
                acc[i].z += p * v4.z; acc[i].w += p * v4.w;
            }
        }
        __syncthreads();
    }

    const float inv = 1.f / l;
    float* orow = Op + ((size_t)sq * BATCH + b) * D_MODEL + h * DK + qd * 16;
#pragma unroll
    for (int i = 0; i < 4; ++i) {
        float4 o;
        o.x = acc[i].x * inv; o.y = acc[i].y * inv;
        o.z = acc[i].z * inv; o.w = acc[i].w * inv;
        *(float4*)(orow + i * 4) = o;
    }
}

// ---------------------------------------------------------------------------
// Fused residual add + LayerNorm over D=512. One block (256 thr) per token.
// O[t] = LN(X[t] + Y[t]) * w + bias   (O may alias X)
// ---------------------------------------------------------------------------
__global__ __launch_bounds__(256) void add_ln(
    const float* __restrict__ X, const float* __restrict__ Y,
    const float* __restrict__ w, const float* __restrict__ bias,
    float* __restrict__ O)
{
    const int t   = blockIdx.x;
    const int tid = threadIdx.x;
    const float* x = X + (size_t)t * D_MODEL;
    const float* y = Y + (size_t)t * D_MODEL;

    float v0 = x[tid] + y[tid];
    float v1 = x[tid + 256] + y[tid + 256];
    float sum = v0 + v1;
    float sq  = v0 * v0 + v1 * v1;
#pragma unroll
    for (int off = 32; off; off >>= 1) {
        sum += __shfl_xor(sum, off);
        sq  += __shfl_xor(sq, off);
    }
    __shared__ float ssum[4], ssq[4];
    const int wid = tid >> 6;
    if ((tid & 63) == 0) { ssum[wid] = sum; ssq[wid] = sq; }
    __syncthreads();
    sum = ssum[0] + ssum[1] + ssum[2] + ssum[3];
    sq  = ssq[0] + ssq[1] + ssq[2] + ssq[3];

    const float mu  = sum * (1.f / D_MODEL);
    const float var = sq * (1.f / D_MODEL) - mu * mu;
    const float rs  = rsqrtf(var + EPS_LN);
    float* o = O + (size_t)t * D_MODEL;
    o[tid]       = (v0 - mu) * rs * w[tid] + bias[tid];
    o[tid + 256] = (v1 - mu) * rs * w[tid + 256] + bias[tid + 256];
}

// ---------------------------------------------------------------------------
// Token embedding + sinusoidal positional encoding. One block per (s,b).
// ---------------------------------------------------------------------------
__global__ __launch_bounds__(256) void embed_pos(
    const int* __restrict__ tokens, const float* __restrict__ emb,
    float* __restrict__ O)
{
    const int t   = blockIdx.x;       // t = s*BATCH + b
    const int s   = t / BATCH;
    const int tid = threadIdx.x;
    const int tok = tokens[t];
    const float LOG1E4 = 9.210340371976184f;  // ln(10000)
#pragma unroll
    for (int i = 0; i < 2; ++i) {
        int d = tid + i * 256;
        float pe;
        if (d < 256) {
            float ang = (float)s * expf(-((float)d * (1.f / 256.f)) * LOG1E4);
            pe = sinf(ang);
        } else {
            float ang = (float)s * expf(-((float)(d - 256) * (1.f / 256.f)) * LOG1E4);
            pe = cosf(ang);
        }
        O[(size_t)t * D_MODEL + d] = emb[(size_t)tok * D_MODEL + d] + pe;
    }
}

// ---------------------------------------------------------------------------
// Host orchestration
// ---------------------------------------------------------------------------
extern "C" void kernel_launch(void* const* d_in, const int* in_sizes, int n_in,
                              void* d_out, int out_size, void* d_ws, size_t ws_size,
                              hipStream_t stream)
{
    const float* src     = (const float*)d_in[0];
    const int*   tokens  = (const int*)d_in[1];
    const float* tok_emb = (const float*)d_in[2];
    const float* enc_qkv_w = (const float*)d_in[3];
    const float* enc_qkv_b = (const float*)d_in[4];
    const float* enc_out_w = (const float*)d_in[5];
    const float* enc_out_b = (const float*)d_in[6];
    const float* enc_l1_w  = (const float*)d_in[7];
    const float* enc_l1_b  = (const float*)d_in[8];
    const float* enc_l2_w  = (const float*)d_in[9];
    const float* enc_l2_b  = (const float*)d_in[10];
    const float* enc_n1_w  = (const float*)d_in[11];
    const float* enc_n1_b  = (const float*)d_in[12];
    const float* enc_n2_w  = (const float*)d_in[13];
    const float* enc_n2_b  = (const float*)d_in[14];
    const float* dec_qkv_w = (const float*)d_in[15];
    const float* dec_qkv_b = (const float*)d_in[16];
    const float* dec_sout_w = (const float*)d_in[17];
    const float* dec_sout_b = (const float*)d_in[18];
    const float* dec_q_w   = (const float*)d_in[19];
    const float* dec_q_b   = (const float*)d_in[20];
    const float* dec_k_w   = (const float*)d_in[21];
    const float* dec_k_b   = (const float*)d_in[22];
    const float* dec_v_w   = (const float*)d_in[23];
    const float* dec_v_b   = (const float*)d_in[24];
    const float* dec_cout_w = (const float*)d_in[25];
    const float* dec_cout_b = (const float*)d_in[26];
    const float* dec_l1_w  = (const float*)d_in[27];
    const float* dec_l1_b  = (const float*)d_in[28];
    const float* dec_l2_w  = (const float*)d_in[29];
    const float* dec_l2_b  = (const float*)d_in[30];
    const float* dec_n1_w  = (const float*)d_in[31];
    const float* dec_n1_b  = (const float*)d_in[32];
    const float* dec_n2_w  = (const float*)d_in[33];
    const float* dec_n2_b  = (const float*)d_in[34];
    const float* dec_n3_w  = (const float*)d_in[35];
    const float* dec_n3_b  = (const float*)d_in[36];
    const float* out_w     = (const float*)d_in[37];
    const float* out_b     = (const float*)d_in[38];

    const int NE = 512 * BATCH;   // 8192 encoder tokens
    const int ND = 128 * BATCH;   // 2048 decoder tokens
    const float scale = 0.125f;   // 1/sqrt(64)

    // Workspace layout (floats)
    float* ws = (float*)d_ws;
    float* Ax = ws;                       // 8192*512  encoder x / memory
    float* Bt = Ax + (size_t)NE * 512;    // 8192*512  encoder tmp
    float* T  = Bt + (size_t)NE * 512;    // 2048*512  decoder tgt
    float* U  = T + (size_t)ND * 512;     // 2048*512  decoder tmp
    float* G  = U + (size_t)ND * 512;     // 8192*2048 big union scratch

    auto gemm = [&](const float* Ain, const float* Win, const float* bin,
                    float* Cout, int N, int M, int K, int relu) {
        dim3 grid((M + 63) / 64, N / 64);
        gemm_nt<<<grid, 256, 0, stream>>>(Ain, Win, bin, Cout, N, M, K, relu);
    };

    // ---------------- Encoder ----------------
    for (int i = 0; i < 6; ++i) {
        const float* xin = (i == 0) ? src : Ax;
        gemm(xin, enc_qkv_w + (size_t)i * 1536 * 512, enc_qkv_b + (size_t)i * 1536,
             G, NE, 1536, 512, 0);
        attn_kern<0><<<dim3(8, N_HEADS, BATCH), 256, 0, stream>>>(
            G, G + 512, G + 1024, Bt, 512, 1536, 1536, scale);
        gemm(Bt, enc_out_w + (size_t)i * 512 * 512, enc_out_b + (size_t)i * 512,
             G, NE, 512, 512, 0);
        add_ln<<<NE, 256, 0, stream>>>(xin, G, enc_n1_w + (size_t)i * 512,
                                       enc_n1_b + (size_t)i * 512, Ax);
        gemm(Ax, enc_l1_w + (size_t)i * 2048 * 512, enc_l1_b + (size_t)i * 2048,
             G, NE, 2048, 512, 1);
        gemm(G, enc_l2_w + (size_t)i * 512 * 2048, enc_l2_b + (size_t)i * 512,
             Bt, NE, 512, 2048, 0);
        add_ln<<<NE, 256, 0, stream>>>(Ax, Bt, enc_n2_w + (size_t)i * 512,
                                       enc_n2_b + (size_t)i * 512, Ax);
    }
    // Ax now holds memory [512,16,512]

    // ---------------- Decoder ----------------
    embed_pos<<<ND, 256, 0, stream>>>(tokens, tok_emb, T);
    for (int i = 0; i < 6; ++i) {
        // causal self-attention
        gemm(T, dec_qkv_w + (size_t)i * 1536 * 512, dec_qkv_b + (size_t)i * 1536,
             G, ND, 1536, 512, 0);
        attn_kern<1><<<dim3(2, N_HEADS, BATCH), 256, 0, stream>>>(
            G, G + 512, G + 1024, U, 128, 1536, 1536, scale);
        gemm(U, dec_sout_w + (size_t)i * 512 * 512, dec_sout_b + (size_t)i * 512,
             G, ND, 512, 512, 0);
        add_ln<<<ND, 256, 0, stream>>>(T, G, dec_n1_w + (size_t)i * 512,
                                       dec_n1_b + (size_t)i * 512, T);
        // cross-attention
        float* Gq = G;
        float* Gk = G + (size_t)ND * 512;
        float* Gv = Gk + (size_t)NE * 512;
        gemm(T,  dec_q_w + (size_t)i * 512 * 512, dec_q_b + (size_t)i * 512, Gq, ND, 512, 512, 0);
        gemm(Ax, dec_k_w + (size_t)i * 512 * 512, dec_k_b + (size_t)i * 512, Gk, NE, 512, 512, 0);
        gemm(Ax, dec_v_w + (size_t)i * 512 * 512, dec_v_b + (size_t)i * 512, Gv, NE, 512, 512, 0);
        attn_kern<0><<<dim3(2, N_HEADS, BATCH), 256, 0, stream>>>(
            Gq, Gk, Gv, U, 512, 512, 512, scale);
        gemm(U, dec_cout_w + (size_t)i * 512 * 512, dec_cout_b + (size_t)i * 512,
             G, ND, 512, 512, 0);
        add_ln<<<ND, 256, 0, stream>>>(T, G, dec_n2_w + (size_t)i * 512,
                                       dec_n2_b + (size_t)i * 512, T);
        // FFN
        gemm(T, dec_l1_w + (size_t)i * 2048 * 512, dec_l1_b + (size_t)i * 2048,
             G, ND, 2048, 512, 1);
        gemm(G, dec_l2_w + (size_t)i * 512 * 2048, dec_l2_b + (size_t)i * 512,
             U, ND, 512, 2048, 0);
        add_ln<<<ND, 256, 0, stream>>>(T, U, dec_n3_w + (size_t)i * 512,
                                       dec_n3_b + (size_t)i * 512, T);
    }

    // ---------------- Output projection ----------------
    gemm(T, out_w, out_b, (float*)d_out, ND, 97, 512, 0);
}

// Round 2
// 4515.173 us; speedup vs baseline: 2.2029x; 2.2029x over previous
//
#include <hip/hip_runtime.h>
#include <hip/hip_bf16.h>
#include <cstddef>
#include <cstdint>

#define D_MODEL 512
#define BATCH 16
#define EPS_LN 1e-5f

typedef __bf16 bf16x8 __attribute__((ext_vector_type(8)));
typedef float f32x4 __attribute__((ext_vector_type(4)));
typedef unsigned short u16x8 __attribute__((ext_vector_type(8)));
typedef unsigned short u16x4 __attribute__((ext_vector_type(4)));
typedef unsigned short u16x2 __attribute__((ext_vector_type(2)));

__device__ __forceinline__ float dot4(float4 a, float4 b) {
    return a.x * b.x + a.y * b.y + a.z * b.z + a.w * b.w;
}

__device__ __forceinline__ void gload_lds16(const void* g, void* l) {
    __builtin_amdgcn_global_load_lds(
        (const __attribute__((address_space(1))) void*)g,
        (__attribute__((address_space(3))) void*)l,
        16, 0, 0);
}

// ---------------------------------------------------------------------------
// MFMA bf16 NT GEMM: C[N,M] = act(A[N,K] @ W[M,K]^T + bias[M])
// 128x128 tile, BK=64, 256 threads (4 waves, 2x2), 4x4 16x16x32 frags/wave.
// LDS XOR-swizzled (slot ^= row&7 on 16B slots); staging via global_load_lds
// with pre-swizzled global source (linear LDS dest). N%128==0, K%64==0.
// M bounds-checked on store only (W must be padded to 128 rows if M%128!=0).
// ---------------------------------------------------------------------------
template <int OUTBF16>
__global__ __launch_bounds__(256) void gemm_mfma(
    const __bf16* __restrict__ A, const __bf16* __restrict__ W,
    const float* __restrict__ bias, void* __restrict__ Cout,
    int N, int M, int K, int relu)
{
    __shared__ __align__(16) char smem[32768];
    char* smemA = smem;
    char* smemW = smem + 16384;

    const int tid  = threadIdx.x;
    const int lane = tid & 63;
    const int wid  = tid >> 6;
    const int wrow = wid >> 1, wcol = wid & 1;
    const int row0 = blockIdx.y * 128;
    const int col0 = blockIdx.x * 128;

    const int lrow  = lane & 15;   // frag row (A) / col (B)
    const int lhalf = lane >> 4;   // k-group 0..3
    const int koff0 = ((lhalf) ^ (lrow & 7)) * 16;        // ks=0 byte offset
    const int koff1 = ((4 + lhalf) ^ (lrow & 7)) * 16;    // ks=1

    // staging: thread -> (row srow within 32-row pass, 16B slot)
    const int srow = tid >> 3;
    const int slot = tid & 7;
    const int sg   = slot ^ (srow & 7);   // inverse-swizzled global k-slot

    f32x4 acc[4][4] = {};

    const __bf16* Abase = A + (size_t)(row0 + srow) * K + sg * 8;
    const __bf16* Wbase = W + (size_t)(col0 + srow) * K + sg * 8;

    for (int kt = 0; kt < K; kt += 64) {
#pragma unroll
        for (int p = 0; p < 4; ++p)
            gload_lds16(Abase + (size_t)p * 32 * K + kt, smemA + p * 4096 + tid * 16);
#pragma unroll
        for (int p = 0; p < 4; ++p)
            gload_lds16(Wbase + (size_t)p * 32 * K + kt, smemW + p * 4096 + tid * 16);
        __syncthreads();

        const char* aB = smemA + (wrow * 64 + lrow) * 128;
        const char* wB = smemW + (wcol * 64 + lrow) * 128;
#pragma unroll
        for (int ks = 0; ks < 2; ++ks) {
            const int ko = ks ? koff1 : koff0;
            bf16x8 af[4], bfr[4];
#pragma unroll
            for (int m = 0; m < 4; ++m) af[m]  = *(const bf16x8*)(aB + m * 2048 + ko);
#pragma unroll
            for (int n = 0; n < 4; ++n) bfr[n] = *(const bf16x8*)(wB + n * 2048 + ko);
#pragma unroll
            for (int m = 0; m < 4; ++m)
#pragma unroll
                for (int n = 0; n < 4; ++n)
                    acc[m][n] = __builtin_amdgcn_mfma_f32_16x16x32_bf16(
                        af[m], bfr[n], acc[m][n], 0, 0, 0);
        }
        __syncthreads();
    }

    // Epilogue: C/D frag layout col=lane&15, row=(lane>>4)*4+j
    const int orow = row0 + wrow * 64 + lhalf * 4;
    const int ocol = col0 + wcol * 64 + lrow;
#pragma unroll
    for (int n = 0; n < 4; ++n) {
        const int c = ocol + n * 16;
        if (c < M) {
            const float bv = bias[c];
#pragma unroll
            for (int m = 0; m < 4; ++m) {
#pragma unroll
                for (int j = 0; j < 4; ++j) {
                    const int r = orow + m * 16 + j;
                    float v = acc[m][n][j] + bv;
                    if (relu) v = fmaxf(v, 0.f);
                    if (OUTBF16) ((__bf16*)Cout)[(size_t)r * M + c] = (__bf16)v;
                    else         ((float*)Cout)[(size_t)r * M + c] = v;
                }
            }
        }
    }
}

// ---------------------------------------------------------------------------
// Flash attention, fp32 in (stride-able QKV), bf16 out at stride D_MODEL.
// Block: 256 thr = 64 q-rows x 4 dim-quarters. grid=(Sq/64, NH, B)
// ---------------------------------------------------------------------------
template <int CAUSAL>
__global__ __launch_bounds__(256) void attn_kern(
    const float* __restrict__ Qp, const float* __restrict__ Kp,
    const float* __restrict__ Vp, __bf16* __restrict__ Op,
    int Skv, int qstride, int kvstride, float scale)
{
    constexpr int KB = 64;
    __shared__ __align__(16) float Ks[KB][68];
    __shared__ __align__(16) float Vs[KB][68];

    const int tid = threadIdx.x;
    const int q0  = blockIdx.x * 64;
    const int h   = blockIdx.y;
    const int b   = blockIdx.z;
    const int r   = tid >> 2;
    const int qd  = tid & 3;
    const int sq  = q0 + r;

    float4 q4[4];
    const float* qrow = Qp + ((size_t)sq * BATCH + b) * qstride + h * 64 + qd * 16;
#pragma unroll
    for (int i = 0; i < 4; ++i) {
        q4[i] = *(const float4*)(qrow + i * 4);
        q4[i].x *= scale; q4[i].y *= scale; q4[i].z *= scale; q4[i].w *= scale;
    }

    float4 acc[4];
#pragma unroll
    for (int i = 0; i < 4; ++i) acc[i] = make_float4(0.f, 0.f, 0.f, 0.f);
    float m = -1e30f, l = 0.f;

    const int nkc = CAUSAL ? (q0 / KB + 1) : (Skv / KB);
    for (int kc = 0; kc < nkc; ++kc) {
        {
            const int kr = tid >> 2, part = tid & 3;
            const size_t tok = ((size_t)(kc * KB + kr) * BATCH + b) * kvstride + h * 64 + part * 16;
#pragma unroll
            for (int i = 0; i < 4; ++i) {
                *(float4*)&Ks[kr][part * 16 + i * 4] = *(const float4*)(Kp + tok + i * 4);
                *(float4*)&Vs[kr][part * 16 + i * 4] = *(const float4*)(Vp + tok + i * 4);
            }
        }
        __syncthreads();

        float ps[KB];
#pragma unroll
        for (int key = 0; key < KB; ++key) {
            float4 k0 = *(const float4*)&Ks[key][qd * 16 + 0];
            float4 k1 = *(const float4*)&Ks[key][qd * 16 + 4];
            float4 k2 = *(const float4*)&Ks[key][qd * 16 + 8];
            float4 k3 = *(const float4*)&Ks[key][qd * 16 + 12];
            ps[key] = dot4(q4[0], k0) + dot4(q4[1], k1) + dot4(q4[2], k2) + dot4(q4[3], k3);
        }
#pragma unroll
        for (int key = 0; key < KB; ++key) {
            ps[key] += __shfl_xor(ps[key], 1, 4);
            ps[key] += __shfl_xor(ps[key], 2, 4);
            if (CAUSAL) {
                if (kc * KB + key > sq) ps[key] = -1e30f;
            }
        }
        float cmax = ps[0];
#pragma unroll
        for (int key = 1; key < KB; ++key) cmax = fmaxf(cmax, ps[key]);
        float mn   = fmaxf(m, cmax);
        float corr = __expf(m - mn);
        l *= corr;
#pragma unroll
        for (int i = 0; i < 4; ++i) {
            acc[i].x *= corr; acc[i].y *= corr; acc[i].z *= corr; acc[i].w *= corr;
        }
        float lsum = 0.f;
#pragma unroll
        for (int key = 0; key < KB; ++key) {
            float p = __expf(ps[key] - mn);
            ps[key] = p;
            lsum += p;
        }
        l += lsum;
        m = mn;
#pragma unroll
        for (int key = 0; key < KB; ++key) {
            float p = ps[key];
#pragma unroll
            for (int i = 0; i < 4; ++i) {
                float4 v4 = *(const float4*)&Vs[key][qd * 16 + i * 4];
                acc[i].x += p * v4.x; acc[i].y += p * v4.y;
                acc[i].z += p * v4.z; acc[i].w += p * v4.w;
            }
        }
        __syncthreads();
    }

    const float inv = 1.f / l;
    __bf16* orow = Op + ((size_t)sq * BATCH + b) * D_MODEL + h * 64 + qd * 16;
#pragma unroll
    for (int i = 0; i < 4; ++i) {
        union { __bf16 h4[4]; u16x4 u; } cv;
        cv.h4[0] = (__bf16)(acc[i].x * inv); cv.h4[1] = (__bf16)(acc[i].y * inv);
        cv.h4[2] = (__bf16)(acc[i].z * inv); cv.h4[3] = (__bf16)(acc[i].w * inv);
        *(u16x4*)(orow + i * 4) = cv.u;
    }
}

// ---------------------------------------------------------------------------
// Residual add + LayerNorm (fp32), dual output fp32 + bf16. One block/token.
// ---------------------------------------------------------------------------
__global__ __launch_bounds__(256) void add_ln(
    const float* __restrict__ X, const float* __restrict__ Y,
    const float* __restrict__ w, const float* __restrict__ bias,
    float* __restrict__ Of, __bf16* __restrict__ Oh)
{
    const int t   = blockIdx.x;
    const int tid = threadIdx.x;
    const float2 x2 = *(const float2*)(X + (size_t)t * D_MODEL + tid * 2);
    const float2 y2 = *(const float2*)(Y + (size_t)t * D_MODEL + tid * 2);
    float v0 = x2.x + y2.x, v1 = x2.y + y2.y;
    float sum = v0 + v1;
    float sq  = v0 * v0 + v1 * v1;
#pragma unroll
    for (int off = 32; off; off >>= 1) {
        sum += __shfl_xor(sum, off);
        sq  += __shfl_xor(sq, off);
    }
    __shared__ float ssum[4], ssq[4];
    const int wid = tid >> 6;
    if ((tid & 63) == 0) { ssum[wid] = sum; ssq[wid] = sq; }
    __syncthreads();
    sum = ssum[0] + ssum[1] + ssum[2] + ssum[3];
    sq  = ssq[0] + ssq[1] + ssq[2] + ssq[3];

    const float mu  = sum * (1.f / D_MODEL);
    const float var = sq * (1.f / D_MODEL) - mu * mu;
    const float rs  = rsqrtf(var + EPS_LN);
    const float2 w2 = *(const float2*)(w + tid * 2);
    const float2 b2 = *(const float2*)(bias + tid * 2);
    float o0 = (v0 - mu) * rs * w2.x + b2.x;
    float o1 = (v1 - mu) * rs * w2.y + b2.y;
    *(float2*)(Of + (size_t)t * D_MODEL + tid * 2) = make_float2(o0, o1);
    union { __bf16 h2[2]; u16x2 u; } cv;
    cv.h2[0] = (__bf16)o0; cv.h2[1] = (__bf16)o1;
    *(u16x2*)(Oh + (size_t)t * D_MODEL + tid * 2) = cv.u;
}

// ---------------------------------------------------------------------------
// Token embedding + positional encoding, dual output. One block per (s,b).
// ---------------------------------------------------------------------------
__global__ __launch_bounds__(256) void embed_pos(
    const int* __restrict__ tokens, const float* __restrict__ emb,
    float* __restrict__ Of, __bf16* __restrict__ Oh)
{
    const int t   = blockIdx.x;
    const int s   = t / BATCH;
    const int tid = threadIdx.x;
    const int tok = tokens[t];
    const float C = 9.210340371976184f / 256.f;  // ln(10000)/256
    const int d = tid * 2;
    const int j = (d < 256) ? d : (d - 256);
    float a0 = (float)s * expf(-(float)j * C);
    float a1 = (float)s * expf(-(float)(j + 1) * C);
    float pe0 = (d < 256) ? sinf(a0) : cosf(a0);
    float pe1 = (d < 256) ? sinf(a1) : cosf(a1);
    const float2 e2 = *(const float2*)(emb + (size_t)tok * D_MODEL + d);
    float o0 = e2.x + pe0, o1 = e2.y + pe1;
    *(float2*)(Of + (size_t)t * D_MODEL + d) = make_float2(o0, o1);
    union { __bf16 h2[2]; u16x2 u; } cv;
    cv.h2[0] = (__bf16)o0; cv.h2[1] = (__bf16)o1;
    *(u16x2*)(Oh + (size_t)t * D_MODEL + d) = cv.u;
}

// ---------------------------------------------------------------------------
// Fused multi-segment fp32 -> bf16 conversion (up to 8 segments, n%8==0).
// ---------------------------------------------------------------------------
struct CvtSeg { const float* s; __bf16* d; int n8; };
struct CvtArgs { CvtSeg seg[8]; int tot8; };

__global__ __launch_bounds__(256) void cvt_multi(CvtArgs a)
{
    const int stride = gridDim.x * 256;
    for (int u = blockIdx.x * 256 + threadIdx.x; u < a.tot8; u += stride) {
        int v = u;
        for (int sgi = 0; sgi < 8; ++sgi) {
            const int n8 = a.seg[sgi].n8;
            if (v < n8) {
                const float4 f0 = ((const float4*)a.seg[sgi].s)[v * 2];
                const float4 f1 = ((const float4*)a.seg[sgi].s)[v * 2 + 1];
                union { __bf16 h[8]; u16x8 u; } c;
                c.h[0] = (__bf16)f0.x; c.h[1] = (__bf16)f0.y;
                c.h[2] = (__bf16)f0.z; c.h[3] = (__bf16)f0.w;
                c.h[4] = (__bf16)f1.x; c.h[5] = (__bf16)f1.y;
                c.h[6] = (__bf16)f1.z; c.h[7] = (__bf16)f1.w;
                ((u16x8*)a.seg[sgi].d)[v] = c.u;
                break;
            }
            v -= n8;
        }
    }
}

// Pad out_w [97,512] -> bf16 [128,512] (zero rows 97..127)
__global__ __launch_bounds__(256) void pad_outw(
    const float* __restrict__ w, __bf16* __restrict__ o)
{
    const int idx = blockIdx.x * 256 + threadIdx.x;  // 0..65535
    const int r = idx >> 9;
    const int c = idx & 511;
    o[idx] = (__bf16)(r < 97 ? w[r * 512 + c] : 0.f);
}

// ---------------------------------------------------------------------------
// Host orchestration
// ---------------------------------------------------------------------------
extern "C" void kernel_launch(void* const* d_in, const int* in_sizes, int n_in,
                              void* d_out, int out_size, void* d_ws, size_t ws_size,
                              hipStream_t stream)
{
    const float* src     = (const float*)d_in[0];
    const int*   tokens  = (const int*)d_in[1];
    const float* tok_emb = (const float*)d_in[2];
    const float* enc_qkv_w = (const float*)d_in[3];
    const float* enc_qkv_b = (const float*)d_in[4];
    const float* enc_out_w = (const float*)d_in[5];
    const float* enc_out_b = (const float*)d_in[6];
    const float* enc_l1_w  = (const float*)d_in[7];
    const float* enc_l1_b  = (const float*)d_in[8];
    const float* enc_l2_w  = (const float*)d_in[9];
    const float* enc_l2_b  = (const float*)d_in[10];
    const float* enc_n1_w  = (const float*)d_in[11];
    const float* enc_n1_b  = (const float*)d_in[12];
    const float* enc_n2_w  = (const float*)d_in[13];
    const float* enc_n2_b  = (const float*)d_in[14];
    const float* dec_qkv_w = (const float*)d_in[15];
    const float* dec_qkv_b = (const float*)d_in[16];
    const float* dec_sout_w = (const float*)d_in[17];
    const float* dec_sout_b = (const float*)d_in[18];
    const float* dec_q_w   = (const float*)d_in[19];
    const float* dec_q_b   = (const float*)d_in[20];
    const float* dec_k_w   = (const float*)d_in[21];
    const float* dec_k_b   = (const float*)d_in[22];
    const float* dec_v_w   = (const float*)d_in[23];
    const float* dec_v_b   = (const float*)d_in[24];
    const float* dec_cout_w = (const float*)d_in[25];
    const float* dec_cout_b = (const float*)d_in[26];
    const float* dec_l1_w  = (const float*)d_in[27];
    const float* dec_l1_b  = (const float*)d_in[28];
    const float* dec_l2_w  = (const float*)d_in[29];
    const float* dec_l2_b  = (const float*)d_in[30];
    const float* dec_n1_w  = (const float*)d_in[31];
    const float* dec_n1_b  = (const float*)d_in[32];
    const float* dec_n2_w  = (const float*)d_in[33];
    const float* dec_n2_b  = (const float*)d_in[34];
    const float* dec_n3_w  = (const float*)d_in[35];
    const float* dec_n3_b  = (const float*)d_in[36];
    const float* out_w     = (const float*)d_in[37];
    const float* out_b     = (const float*)d_in[38];

    const int NE = 512 * BATCH;   // 8192
    const int ND = 128 * BATCH;   // 2048
    const float scale = 0.125f;

    // -------- workspace layout (bytes) --------
    char* w8 = (char*)d_ws;
    float*  Ax_f = (float*) (w8 + 0);          // 16,777,216  enc residual fp32
    float*  T_f  = (float*) (w8 + 16777216);   //  4,194,304  dec residual fp32
    __bf16* Ax_h = (__bf16*)(w8 + 20971520);   //  8,388,608  enc bf16 copy
    __bf16* T_h  = (__bf16*)(w8 + 29360128);   //  2,097,152  dec bf16 copy
    __bf16* AO_h = (__bf16*)(w8 + 31457280);   //  8,388,608  attn out bf16
    __bf16* Wk   = (__bf16*)(w8 + 39845888);   //  9,437,184  weight scratch
    __bf16* OWp  = (__bf16*)(w8 + 49283072);   //    131,072  padded out_w
    char*   Gb   = w8 + 49414144;              // 50,331,648  big union
    float*  Gf   = (float*)Gb;                 // qkv fp32 / proj-out fp32
    __bf16* Gh   = (__bf16*)Gb;                // ffn hidden bf16
    float*  Y2f  = (float*)(Gb + 33554432);    // ffn2 out fp32
    float*  Gq   = (float*)Gb;
    float*  Gk   = (float*)(Gb + 4194304);
    float*  Gv   = (float*)(Gb + 20971520);

    auto gemm = [&](const __bf16* Am, const __bf16* Wm, const float* bv, void* C,
                    int N, int M, int K, int relu, bool outbf) {
        dim3 grid((M + 127) / 128, N / 128);
        if (outbf) gemm_mfma<1><<<grid, 256, 0, stream>>>(Am, Wm, bv, C, N, M, K, relu);
        else       gemm_mfma<0><<<grid, 256, 0, stream>>>(Am, Wm, bv, C, N, M, K, relu);
    };
    auto cvt = [&](CvtArgs& a) {
        int tot = 0;
        for (int i = 0; i < 8; ++i) tot += a.seg[i].n8;
        a.tot8 = tot;
        cvt_multi<<<1024, 256, 0, stream>>>(a);
    };

    // src -> bf16
    {
        CvtArgs a = {};
        a.seg[0] = { src, Ax_h, NE * 512 / 8 };
        cvt(a);
    }

    // ---------------- Encoder ----------------
    __bf16* wqkv = Wk;
    __bf16* wout = Wk + 786432;
    __bf16* wl1  = Wk + 1048576;
    __bf16* wl2  = Wk + 2097152;
    for (int i = 0; i < 6; ++i) {
        CvtArgs a = {};
        a.seg[0] = { enc_qkv_w + (size_t)i * 786432,  wqkv, 786432 / 8 };
        a.seg[1] = { enc_out_w + (size_t)i * 262144,  wout, 262144 / 8 };
        a.seg[2] = { enc_l1_w  + (size_t)i * 1048576, wl1, 1048576 / 8 };
        a.seg[3] = { enc_l2_w  + (size_t)i * 1048576, wl2, 1048576 / 8 };
        cvt(a);

        gemm(Ax_h, wqkv, enc_qkv_b + (size_t)i * 1536, Gf, NE, 1536, 512, 0, false);
        attn_kern<0><<<dim3(8, 8, BATCH), 256, 0, stream>>>(
            Gf, Gf + 512, Gf + 1024, AO_h, 512, 1536, 1536, scale);
        gemm(AO_h, wout, enc_out_b + (size_t)i * 512, Gf, NE, 512, 512, 0, false);
        add_ln<<<NE, 256, 0, stream>>>((i == 0) ? src : Ax_f, Gf,
                                       enc_n1_w + (size_t)i * 512, enc_n1_b + (size_t)i * 512,
                                       Ax_f, Ax_h);
        gemm(Ax_h, wl1, enc_l1_b + (size_t)i * 2048, Gh, NE, 2048, 512, 1, true);
        gemm(Gh, wl2, enc_l2_b + (size_t)i * 512, Y2f, NE, 512, 2048, 0, false);
        add_ln<<<NE, 256, 0, stream>>>(Ax_f, Y2f,
                                       enc_n2_w + (size_t)i * 512, enc_n2_b + (size_t)i * 512,
                                       Ax_f, Ax_h);
    }
    // Ax_f / Ax_h = memory

    // ---------------- Decoder ----------------
    embed_pos<<<ND, 256, 0, stream>>>(tokens, tok_emb, T_f, T_h);
    __bf16* dqkv = Wk;
    __bf16* dsout = Wk + 786432;
    __bf16* dq   = Wk + 1048576;
    __bf16* dk   = Wk + 1310720;
    __bf16* dv   = Wk + 1572864;
    __bf16* dcout = Wk + 1835008;
    __bf16* dl1  = Wk + 2097152;
    __bf16* dl2  = Wk + 3145728;
    for (int i = 0; i < 6; ++i) {
        CvtArgs a = {};
        a.seg[0] = { dec_qkv_w  + (size_t)i * 786432,  dqkv,  786432 / 8 };
        a.seg[1] = { dec_sout_w + (size_t)i * 262144,  dsout, 262144 / 8 };
        a.seg[2] = { dec_q_w    + (size_t)i * 262144,  dq,    262144 / 8 };
        a.seg[3] = { dec_k_w    + (size_t)i * 262144,  dk,    262144 / 8 };
        a.seg[4] = { dec_v_w    + (size_t)i * 262144,  dv,    262144 / 8 };
        a.seg[5] = { dec_cout_w + (size_t)i * 262144,  dcout, 262144 / 8 };
        a.seg[6] = { dec_l1_w   + (size_t)i * 1048576, dl1,  1048576 / 8 };
        a.seg[7] = { dec_l2_w   + (size_t)i * 1048576, dl2,  1048576 / 8 };
        cvt(a);

        // causal self-attn
        gemm(T_h, dqkv, dec_qkv_b + (size_t)i * 1536, Gf, ND, 1536, 512, 0, false);
        attn_kern<1><<<dim3(2, 8, BATCH), 256, 0, stream>>>(
            Gf, Gf + 512, Gf + 1024, AO_h, 128, 1536, 1536, scale);
        gemm(AO_h, dsout, dec_sout_b + (size_t)i * 512, Gf, ND, 512, 512, 0, false);
        add_ln<<<ND, 256, 0, stream>>>(T_f, Gf,
                                       dec_n1_w + (size_t)i * 512, dec_n1_b + (size_t)i * 512,
                                       T_f, T_h);
        // cross-attn
        gemm(T_h,  dq, dec_q_b + (size_t)i * 512, Gq, ND, 512, 512, 0, false);
        gemm(Ax_h, dk, dec_k_b + (size_t)i * 512, Gk, NE, 512, 512, 0, false);
        gemm(Ax_h, dv, dec_v_b + (size_t)i * 512, Gv, NE, 512, 512, 0, false);
        attn_kern<0><<<dim3(2, 8, BATCH), 256, 0, stream>>>(
            Gq, Gk, Gv, AO_h, 512, 512, 512, scale);
        gemm(AO_h, dcout, dec_cout_b + (size_t)i * 512, Gf, ND, 512, 512, 0, false);
        add_ln<<<ND, 256, 0, stream>>>(T_f, Gf,
                                       dec_n2_w + (size_t)i * 512, dec_n2_b + (size_t)i * 512,
                                       T_f, T_h);
        // FFN
        gemm(T_h, dl1, dec_l1_b + (size_t)i * 2048, Gh, ND, 2048, 512, 1, true);
        gemm(Gh, dl2, dec_l2_b + (size_t)i * 512, Y2f, ND, 512, 2048, 0, false);
        add_ln<<<ND, 256, 0, stream>>>(T_f, Y2f,
                                       dec_n3_w + (size_t)i * 512, dec_n3_b + (size_t)i * 512,
                                       T_f, T_h);
    }

    // ---------------- Output projection ----------------
    pad_outw<<<256, 256, 0, stream>>>(out_w, OWp);
    gemm(T_h, OWp, out_b, (float*)d_out, ND, 97, 512, 0, false);
}

// Round 3
// 2170.803 us; speedup vs baseline: 4.5819x; 2.0800x over previous
//
#include <hip/hip_runtime.h>
#include <hip/hip_bf16.h>
#include <cstddef>
#include <cstdint>

#define D_MODEL 512
#define BATCH 16
#define EPS_LN 1e-5f

typedef __bf16 bf16x8 __attribute__((ext_vector_type(8)));
typedef float f32x4 __attribute__((ext_vector_type(4)));
typedef unsigned short u16x8 __attribute__((ext_vector_type(8)));
typedef unsigned short u16x4 __attribute__((ext_vector_type(4)));
typedef unsigned short u16x2 __attribute__((ext_vector_type(2)));

__device__ __forceinline__ void gload_lds16(const void* g, void* l) {
    __builtin_amdgcn_global_load_lds(
        (const __attribute__((address_space(1))) void*)g,
        (__attribute__((address_space(3))) void*)l,
        16, 0, 0);
}

// ---------------------------------------------------------------------------
// MFMA bf16 NT GEMM: C[N,M] = act(A[N,K] @ W[M,K]^T + bias[M])
// 128x128 tile, BK=64, 256 threads (4 waves 2x2), 4x4 16x16x32 frags/wave.
// ---------------------------------------------------------------------------
template <int OUTBF16>
__global__ __launch_bounds__(256) void gemm_mfma(
    const __bf16* __restrict__ A, const __bf16* __restrict__ W,
    const float* __restrict__ bias, void* __restrict__ Cout,
    int N, int M, int K, int relu)
{
    __shared__ __align__(16) char smem[32768];
    char* smemA = smem;
    char* smemW = smem + 16384;

    const int tid  = threadIdx.x;
    const int lane = tid & 63;
    const int wid  = tid >> 6;
    const int wrow = wid >> 1, wcol = wid & 1;
    const int row0 = blockIdx.y * 128;
    const int col0 = blockIdx.x * 128;

    const int lrow  = lane & 15;
    const int lhalf = lane >> 4;
    const int koff0 = ((lhalf) ^ (lrow & 7)) * 16;
    const int koff1 = ((4 + lhalf) ^ (lrow & 7)) * 16;

    const int srow = tid >> 3;
    const int slot = tid & 7;
    const int sg   = slot ^ (srow & 7);

    f32x4 acc[4][4] = {};

    const __bf16* Abase = A + (size_t)(row0 + srow) * K + sg * 8;
    const __bf16* Wbase = W + (size_t)(col0 + srow) * K + sg * 8;

    for (int kt = 0; kt < K; kt += 64) {
#pragma unroll
        for (int p = 0; p < 4; ++p)
            gload_lds16(Abase + (size_t)p * 32 * K + kt, smemA + p * 4096 + tid * 16);
#pragma unroll
        for (int p = 0; p < 4; ++p)
            gload_lds16(Wbase + (size_t)p * 32 * K + kt, smemW + p * 4096 + tid * 16);
        __syncthreads();

        const char* aB = smemA + (wrow * 64 + lrow) * 128;
        const char* wB = smemW + (wcol * 64 + lrow) * 128;
#pragma unroll
        for (int ks = 0; ks < 2; ++ks) {
            const int ko = ks ? koff1 : koff0;
            bf16x8 af[4], bfr[4];
#pragma unroll
            for (int m = 0; m < 4; ++m) af[m]  = *(const bf16x8*)(aB + m * 2048 + ko);
#pragma unroll
            for (int n = 0; n < 4; ++n) bfr[n] = *(const bf16x8*)(wB + n * 2048 + ko);
#pragma unroll
            for (int m = 0; m < 4; ++m)
#pragma unroll
                for (int n = 0; n < 4; ++n)
                    acc[m][n] = __builtin_amdgcn_mfma_f32_16x16x32_bf16(
                        af[m], bfr[n], acc[m][n], 0, 0, 0);
        }
        __syncthreads();
    }

    const int orow = row0 + wrow * 64 + lhalf * 4;
    const int ocol = col0 + wcol * 64 + lrow;
#pragma unroll
    for (int n = 0; n < 4; ++n) {
        const int c = ocol + n * 16;
        if (c < M) {
            const float bv = bias[c];
#pragma unroll
            for (int m = 0; m < 4; ++m) {
#pragma unroll
                for (int j = 0; j < 4; ++j) {
                    const int r = orow + m * 16 + j;
                    float v = acc[m][n][j] + bv;
                    if (relu) v = fmaxf(v, 0.f);
                    if (OUTBF16) ((__bf16*)Cout)[(size_t)r * M + c] = (__bf16)v;
                    else         ((float*)Cout)[(size_t)r * M + c] = v;
                }
            }
        }
    }
}

// ---------------------------------------------------------------------------
// V transpose: V[(s*B+b)*stride + voff + h*64 + d] (bf16) ->
//              VT[((b*8+h)*64 + d)*S + s] (bf16).  grid (S/64, 8, 16).
// ---------------------------------------------------------------------------
__global__ __launch_bounds__(256) void transpose_v(
    const __bf16* __restrict__ V, __bf16* __restrict__ VT,
    int stride, int voff, int S)
{
    __shared__ __align__(16) char smem[8192];   // [64 s][64 d] bf16 linear
    const int tid = threadIdx.x;
    const int kc = blockIdx.x, h = blockIdx.y, b = blockIdx.z;
    const int srow = tid >> 3, slot = tid & 7;
#pragma unroll
    for (int p = 0; p < 2; ++p) {
        int r = p * 32 + srow;
        const __bf16* src = V + ((size_t)(kc * 64 + r) * BATCH + b) * stride
                              + voff + h * 64 + slot * 8;
        gload_lds16(src, smem + (p * 256 + tid) * 16);
    }
    __syncthreads();
    const int l = tid & 63, w = tid >> 6;
    const int d2 = w * 8 + (l >> 3);     // dword column -> d = 2*d2, 2*d2+1
    const int s0 = (l & 7) * 8;          // 8 consecutive s values
    unsigned rows[8];
#pragma unroll
    for (int e = 0; e < 8; ++e)
        rows[e] = *(const unsigned*)(smem + (s0 + e) * 128 + d2 * 4);
    union { __bf16 h8[8]; u16x8 u; } r0, r1;
#pragma unroll
    for (int e = 0; e < 8; ++e) {
        r0.h8[e] = ((const __bf16*)&rows[e])[0];
        r1.h8[e] = ((const __bf16*)&rows[e])[1];
    }
    size_t obase = ((size_t)(b * 8 + h) * 64 + d2 * 2) * S + kc * 64 + s0;
    *(u16x8*)(VT + obase)     = r0.u;
    *(u16x8*)(VT + obase + S) = r1.u;
}

// ---------------------------------------------------------------------------
// MFMA flash attention. Block = 64 q-rows (4 waves x 16), 64-key chunks.
// Q,K bf16 token rows; VT bf16 [(b*8+h)*64+d][Skv]. Out bf16 [token][512].
// Swapped QK^T (mfma(K,Q)) -> lane owns q=lane&15; P via wave-private
// swizzled LDS; PV with VT as B-operand. grid (Sq/64, 8, 16).
// ---------------------------------------------------------------------------
template <int CAUSAL>
__global__ __launch_bounds__(256) void attn_mfma(
    const __bf16* __restrict__ Qb, const __bf16* __restrict__ Kb,
    const __bf16* __restrict__ VT, __bf16* __restrict__ Op,
    int Skv, int qstride, int kstride, int koff, float scale)
{
    __shared__ __align__(16) char smem[24576];
    char* Ksm = smem;            // [64 key][64 dk] bf16, slot-swizzled
    char* Vsm = smem + 8192;     // [64 d][64 key] bf16, slot-swizzled
    const int tid = threadIdx.x;
    const int l   = tid & 63;
    const int w   = tid >> 6;
    char* Psm = smem + 16384 + w * 2048;   // wave-private [16 q][64 key]

    const int qc = blockIdx.x;
    const int h  = blockIdx.y;
    const int b  = blockIdx.z;
    const int l15 = l & 15;
    const int g   = l >> 4;
    const int sw  = l15 & 7;

    // Q fragments (B-operand): q row = qc*64 + w*16 + l15
    const int sq = qc * 64 + w * 16 + l15;
    const __bf16* qrow = Qb + ((size_t)sq * BATCH + b) * qstride + h * 64 + g * 8;
    const bf16x8 qf0 = *(const bf16x8*)(qrow);
    const bf16x8 qf1 = *(const bf16x8*)(qrow + 32);

    const int srow = tid >> 3;
    const int slot = tid & 7;

    f32x4 acc[4] = {};            // O: rows q=4g+j, col d=l15+16n
    float m_run = -1e30f, l_run = 0.f;

    const int nkc = CAUSAL ? (qc + 1) : (Skv >> 6);
    for (int kc = 0; kc < nkc; ++kc) {
        // ---- stage K and VT chunks (swizzled: linear dest, pre-swz source)
#pragma unroll
        for (int p = 0; p < 2; ++p) {
            const int r  = p * 32 + srow;
            const int sg = (slot ^ (r & 7)) * 8;
            const __bf16* ksrc = Kb + ((size_t)(kc * 64 + r) * BATCH + b) * kstride
                                    + koff + h * 64 + sg;
            gload_lds16(ksrc, Ksm + (p * 256 + tid) * 16);
            const __bf16* vsrc = VT + ((size_t)((b * 8 + h) * 64 + r)) * Skv
                                    + kc * 64 + sg;
            gload_lds16(vsrc, Vsm + (p * 256 + tid) * 16);
        }
        __syncthreads();

        // ---- QK^T (swapped): st[f] = S^T[key = f*16+4g+j][q = l15]
        f32x4 st[4];
#pragma unroll
        for (int f = 0; f < 4; ++f) {
            const char* kr = Ksm + (f * 16 + l15) * 128;
            bf16x8 ka0 = *(const bf16x8*)(kr + ((g ^ sw) * 16));
            bf16x8 ka1 = *(const bf16x8*)(kr + (((4 + g) ^ sw) * 16));
            f32x4 z = {};
            z = __builtin_amdgcn_mfma_f32_16x16x32_bf16(ka0, qf0, z, 0, 0, 0);
            st[f] = __builtin_amdgcn_mfma_f32_16x16x32_bf16(ka1, qf1, z, 0, 0, 0);
        }

        // ---- scale + mask + online softmax (lane owns q = l15)
        float rmax = -1e30f;
#pragma unroll
        for (int f = 0; f < 4; ++f)
#pragma unroll
            for (int j = 0; j < 4; ++j) {
                float v = st[f][j] * scale;
                if (CAUSAL) {
                    if (kc * 64 + f * 16 + g * 4 + j > sq) v = -1e30f;
                }
                st[f][j] = v;
                rmax = fmaxf(rmax, v);
            }
        rmax = fmaxf(rmax, __shfl_xor(rmax, 16, 64));
        rmax = fmaxf(rmax, __shfl_xor(rmax, 32, 64));
        const float mn = fmaxf(m_run, rmax);
        const float corr = __expf(m_run - mn);
        m_run = mn;
        float rsum = 0.f;
#pragma unroll
        for (int f = 0; f < 4; ++f)
#pragma unroll
            for (int j = 0; j < 4; ++j) {
                float p = __expf(st[f][j] - mn);
                st[f][j] = p;
                rsum += p;
            }
        rsum += __shfl_xor(rsum, 16, 64);
        rsum += __shfl_xor(rsum, 32, 64);
        l_run = l_run * corr + rsum;

        // rescale O-acc: rows q=4g+j need corr from lane 16g + 4g + j
#pragma unroll
        for (int j = 0; j < 4; ++j) {
            const float cj = __shfl(corr, g * 20 + j, 64);
            acc[0][j] *= cj; acc[1][j] *= cj; acc[2][j] *= cj; acc[3][j] *= cj;
        }

        // ---- pack P -> bf16, write wave-private P LDS [16 q][64 key] swz
#pragma unroll
        for (int f = 0; f < 4; ++f)
#pragma unroll
            for (int j2 = 0; j2 < 2; ++j2) {
                union { __bf16 h2[2]; unsigned u; } cv;
                cv.h2[0] = (__bf16)st[f][2 * j2];
                cv.h2[1] = (__bf16)st[f][2 * j2 + 1];
                const int key0 = 16 * f + 4 * g + 2 * j2;
                const int byte = l15 * 128 + (((key0 >> 3) ^ sw) * 16) + (key0 & 7) * 2;
                *(unsigned*)(Psm + byte) = cv.u;
            }

        // ---- PV: acc[n] += P x VT  (wave-private P, no barrier needed)
#pragma unroll
        for (int ks = 0; ks < 2; ++ks) {
            const int so = ((4 * ks + g) ^ sw) * 16;
            bf16x8 pa = *(const bf16x8*)(Psm + l15 * 128 + so);
#pragma unroll
            for (int n = 0; n < 4; ++n) {
                bf16x8 vb = *(const bf16x8*)(Vsm + (n * 16 + l15) * 128 + so);
                acc[n] = __builtin_amdgcn_mfma_f32_16x16x32_bf16(pa, vb, acc[n], 0, 0, 0);
            }
        }
        __syncthreads();
    }

    const float inv = 1.f / l_run;
#pragma unroll
    for (int j = 0; j < 4; ++j) {
        const float ij = __shfl(inv, g * 20 + j, 64);
        const int s = qc * 64 + w * 16 + g * 4 + j;
        __bf16* orow = Op + ((size_t)s * BATCH + b) * D_MODEL + h * 64 + l15;
#pragma unroll
        for (int n = 0; n < 4; ++n)
            orow[n * 16] = (__bf16)(acc[n][j] * ij);
    }
}

// ---------------------------------------------------------------------------
// Residual add + LayerNorm: X fp32 + Y bf16 -> fp32 + bf16. One block/token.
// ---------------------------------------------------------------------------
__global__ __launch_bounds__(256) void add_ln(
    const float* __restrict__ X, const __bf16* __restrict__ Y,
    const float* __restrict__ w, const float* __restrict__ bias,
    float* __restrict__ Of, __bf16* __restrict__ Oh)
{
    const int t   = blockIdx.x;
    const int tid = threadIdx.x;
    const float2 x2 = *(const float2*)(X + (size_t)t * D_MODEL + tid * 2);
    const u16x2 yv = *(const u16x2*)(Y + (size_t)t * D_MODEL + tid * 2);
    union { u16x2 u; __bf16 h2[2]; } yc; yc.u = yv;
    float v0 = x2.x + (float)yc.h2[0], v1 = x2.y + (float)yc.h2[1];
    float sum = v0 + v1;
    float sq  = v0 * v0 + v1 * v1;
#pragma unroll
    for (int off = 32; off; off >>= 1) {
        sum += __shfl_xor(sum, off);
        sq  += __shfl_xor(sq, off);
    }
    __shared__ float ssum[4], ssq[4];
    const int wid = tid >> 6;
    if ((tid & 63) == 0) { ssum[wid] = sum; ssq[wid] = sq; }
    __syncthreads();
    sum = ssum[0] + ssum[1] + ssum[2] + ssum[3];
    sq  = ssq[0] + ssq[1] + ssq[2] + ssq[3];

    const float mu  = sum * (1.f / D_MODEL);
    const float var = sq * (1.f / D_MODEL) - mu * mu;
    const float rs  = rsqrtf(var + EPS_LN);
    const float2 w2 = *(const float2*)(w + tid * 2);
    const float2 b2 = *(const float2*)(bias + tid * 2);
    float o0 = (v0 - mu) * rs * w2.x + b2.x;
    float o1 = (v1 - mu) * rs * w2.y + b2.y;
    *(float2*)(Of + (size_t)t * D_MODEL + tid * 2) = make_float2(o0, o1);
    union { __bf16 h2[2]; u16x2 u; } cv;
    cv.h2[0] = (__bf16)o0; cv.h2[1] = (__bf16)o1;
    *(u16x2*)(Oh + (size_t)t * D_MODEL + tid * 2) = cv.u;
}

// ---------------------------------------------------------------------------
// Token embedding + positional encoding, dual output. One block per (s,b).
// ---------------------------------------------------------------------------
__global__ __launch_bounds__(256) void embed_pos(
    const int* __restrict__ tokens, const float* __restrict__ emb,
    float* __restrict__ Of, __bf16* __restrict__ Oh)
{
    const int t   = blockIdx.x;
    const int s   = t / BATCH;
    const int tid = threadIdx.x;
    const int tok = tokens[t];
    const float C = 9.210340371976184f / 256.f;
    const int d = tid * 2;
    const int j = (d < 256) ? d : (d - 256);
    float a0 = (float)s * expf(-(float)j * C);
    float a1 = (float)s * expf(-(float)(j + 1) * C);
    float pe0 = (d < 256) ? sinf(a0) : cosf(a0);
    float pe1 = (d < 256) ? sinf(a1) : cosf(a1);
    const float2 e2 = *(const float2*)(emb + (size_t)tok * D_MODEL + d);
    float o0 = e2.x + pe0, o1 = e2.y + pe1;
    *(float2*)(Of + (size_t)t * D_MODEL + d) = make_float2(o0, o1);
    union { __bf16 h2[2]; u16x2 u; } cv;
    cv.h2[0] = (__bf16)o0; cv.h2[1] = (__bf16)o1;
    *(u16x2*)(Oh + (size_t)t * D_MODEL + d) = cv.u;
}

// ---------------------------------------------------------------------------
// Multi-segment fp32 -> bf16 conversion.
// ---------------------------------------------------------------------------
struct CvtSeg { const float* s; __bf16* d; int n8; };
struct CvtArgs { CvtSeg seg[8]; int tot8; };

__global__ __launch_bounds__(256) void cvt_multi(CvtArgs a)
{
    const int stride = gridDim.x * 256;
    for (int u = blockIdx.x * 256 + threadIdx.x; u < a.tot8; u += stride) {
        int v = u;
        for (int sgi = 0; sgi < 8; ++sgi) {
            const int n8 = a.seg[sgi].n8;
            if (v < n8) {
                const float4 f0 = ((const float4*)a.seg[sgi].s)[v * 2];
                const float4 f1 = ((const float4*)a.seg[sgi].s)[v * 2 + 1];
                union { __bf16 h[8]; u16x8 u; } c;
                c.h[0] = (__bf16)f0.x; c.h[1] = (__bf16)f0.y;
                c.h[2] = (__bf16)f0.z; c.h[3] = (__bf16)f0.w;
                c.h[4] = (__bf16)f1.x; c.h[5] = (__bf16)f1.y;
                c.h[6] = (__bf16)f1.z; c.h[7] = (__bf16)f1.w;
                ((u16x8*)a.seg[sgi].d)[v] = c.u;
                break;
            }
            v -= n8;
        }
    }
}

__global__ __launch_bounds__(256) void pad_outw(
    const float* __restrict__ w, __bf16* __restrict__ o)
{
    const int idx = blockIdx.x * 256 + threadIdx.x;
    const int r = idx >> 9;
    const int c = idx & 511;
    o[idx] = (__bf16)(r < 97 ? w[r * 512 + c] : 0.f);
}

// ---------------------------------------------------------------------------
// Host orchestration
// ---------------------------------------------------------------------------
extern "C" void kernel_launch(void* const* d_in, const int* in_sizes, int n_in,
                              void* d_out, int out_size, void* d_ws, size_t ws_size,
                              hipStream_t stream)
{
    const float* src     = (const float*)d_in[0];
    const int*   tokens  = (const int*)d_in[1];
    const float* tok_emb = (const float*)d_in[2];
    const float* enc_qkv_w = (const float*)d_in[3];
    const float* enc_qkv_b = (const float*)d_in[4];
    const float* enc_out_w = (const float*)d_in[5];
    const float* enc_out_b = (const float*)d_in[6];
    const float* enc_l1_w  = (const float*)d_in[7];
    const float* enc_l1_b  = (const float*)d_in[8];
    const float* enc_l2_w  = (const float*)d_in[9];
    const float* enc_l2_b  = (const float*)d_in[10];
    const float* enc_n1_w  = (const float*)d_in[11];
    const float* enc_n1_b  = (const float*)d_in[12];
    const float* enc_n2_w  = (const float*)d_in[13];
    const float* enc_n2_b  = (const float*)d_in[14];
    const float* dec_qkv_w = (const float*)d_in[15];
    const float* dec_qkv_b = (const float*)d_in[16];
    const float* dec_sout_w = (const float*)d_in[17];
    const float* dec_sout_b = (const float*)d_in[18];
    const float* dec_q_w   = (const float*)d_in[19];
    const float* dec_q_b   = (const float*)d_in[20];
    const float* dec_k_w   = (const float*)d_in[21];
    const float* dec_k_b   = (const float*)d_in[22];
    const float* dec_v_w   = (const float*)d_in[23];
    const float* dec_v_b   = (const float*)d_in[24];
    const float* dec_cout_w = (const float*)d_in[25];
    const float* dec_cout_b = (const float*)d_in[26];
    const float* dec_l1_w  = (const float*)d_in[27];
    const float* dec_l1_b  = (const float*)d_in[28];
    const float* dec_l2_w  = (const float*)d_in[29];
    const float* dec_l2_b  = (const float*)d_in[30];
    const float* dec_n1_w  = (const float*)d_in[31];
    const float* dec_n1_b  = (const float*)d_in[32];
    const float* dec_n2_w  = (const float*)d_in[33];
    const float* dec_n2_b  = (const float*)d_in[34];
    const float* dec_n3_w  = (const float*)d_in[35];
    const float* dec_n3_b  = (const float*)d_in[36];
    const float* out_w     = (const float*)d_in[37];
    const float* out_b     = (const float*)d_in[38];

    const int NE = 512 * BATCH;   // 8192
    const int ND = 128 * BATCH;   // 2048
    const float scale = 0.125f;

    // -------- workspace layout (99,745,792 bytes total) --------
    char* w8 = (char*)d_ws;
    float*  Ax_f = (float*) (w8 + 0);          // 16 MB enc residual fp32
    float*  T_f  = (float*) (w8 + 16777216);   //  4 MB dec residual fp32
    __bf16* Ax_h = (__bf16*)(w8 + 20971520);   //  8 MB enc bf16
    __bf16* T_h  = (__bf16*)(w8 + 29360128);   //  2 MB dec bf16
    __bf16* AO_h = (__bf16*)(w8 + 31457280);   //  8 MB attn out bf16
    __bf16* Wk   = (__bf16*)(w8 + 39845888);   //  9 MB weight scratch
    __bf16* OWp  = (__bf16*)(w8 + 49283072);   //  0.13 MB padded out_w
    __bf16* VT   = (__bf16*)(w8 + 49414144);   //  8 MB V-transpose
    char*   Gb   = w8 + 57802752;              // 32 MB union
    __bf16* Gqkv = (__bf16*)Gb;                // qkv bf16 [N][1536]
    __bf16* Gh   = (__bf16*)Gb;                // ffn hidden bf16 [N][2048]
    __bf16* Gq   = (__bf16*)Gb;                // cross q bf16 [2048][512]
    __bf16* Gk   = (__bf16*)(Gb + 2097152);    // cross k bf16 [8192][512]
    __bf16* Gv   = (__bf16*)(Gb + 10485760);   // cross v bf16 [8192][512]
    __bf16* Y_h  = (__bf16*)(w8 + 91357184);   //  8 MB residual-Y bf16

    auto gemm = [&](const __bf16* Am, const __bf16* Wm, const float* bv, void* C,
                    int N, int M, int K, int relu, bool outbf) {
        dim3 grid((M + 127) / 128, N / 128);
        if (outbf) gemm_mfma<1><<<grid, 256, 0, stream>>>(Am, Wm, bv, C, N, M, K, relu);
        else       gemm_mfma<0><<<grid, 256, 0, stream>>>(Am, Wm, bv, C, N, M, K, relu);
    };
    auto cvt = [&](CvtArgs& a) {
        int tot = 0;
        for (int i = 0; i < 8; ++i) tot += a.seg[i].n8;
        a.tot8 = tot;
        cvt_multi<<<1024, 256, 0, stream>>>(a);
    };

    { CvtArgs a = {}; a.seg[0] = { src, Ax_h, NE * 512 / 8 }; cvt(a); }

    // ---------------- Encoder ----------------
    __bf16* wqkv = Wk;
    __bf16* wout = Wk + 786432;
    __bf16* wl1  = Wk + 1048576;
    __bf16* wl2  = Wk + 2097152;
    for (int i = 0; i < 6; ++i) {
        CvtArgs a = {};
        a.seg[0] = { enc_qkv_w + (size_t)i * 786432,  wqkv, 786432 / 8 };
        a.seg[1] = { enc_out_w + (size_t)i * 262144,  wout, 262144 / 8 };
        a.seg[2] = { enc_l1_w  + (size_t)i * 1048576, wl1, 1048576 / 8 };
        a.seg[3] = { enc_l2_w  + (size_t)i * 1048576, wl2, 1048576 / 8 };
        cvt(a);

        gemm(Ax_h, wqkv, enc_qkv_b + (size_t)i * 1536, Gqkv, NE, 1536, 512, 0, true);
        transpose_v<<<dim3(8, 8, BATCH), 256, 0, stream>>>(Gqkv, VT, 1536, 1024, 512);
        attn_mfma<0><<<dim3(8, 8, BATCH), 256, 0, stream>>>(
            Gqkv, Gqkv, VT, AO_h, 512, 1536, 1536, 512, scale);
        gemm(AO_h, wout, enc_out_b + (size_t)i * 512, Y_h, NE, 512, 512, 0, true);
        add_ln<<<NE, 256, 0, stream>>>((i == 0) ? src : Ax_f, Y_h,
                                       enc_n1_w + (size_t)i * 512, enc_n1_b + (size_t)i * 512,
                                       Ax_f, Ax_h);
        gemm(Ax_h, wl1, enc_l1_b + (size_t)i * 2048, Gh, NE, 2048, 512, 1, true);
        gemm(Gh, wl2, enc_l2_b + (size_t)i * 512, Y_h, NE, 512, 2048, 0, true);
        add_ln<<<NE, 256, 0, stream>>>(Ax_f, Y_h,
                                       enc_n2_w + (size_t)i * 512, enc_n2_b + (size_t)i * 512,
                                       Ax_f, Ax_h);
    }

    // ---------------- Decoder ----------------
    embed_pos<<<ND, 256, 0, stream>>>(tokens, tok_emb, T_f, T_h);
    __bf16* dqkv = Wk;
    __bf16* dsout = Wk + 786432;
    __bf16* dq   = Wk + 1048576;
    __bf16* dk   = Wk + 1310720;
    __bf16* dv   = Wk + 1572864;
    __bf16* dcout = Wk + 1835008;
    __bf16* dl1  = Wk + 2097152;
    __bf16* dl2  = Wk + 3145728;
    for (int i = 0; i < 6; ++i) {
        CvtArgs a = {};
        a.seg[0] = { dec_qkv_w  + (size_t)i * 786432,  dqkv,  786432 / 8 };
        a.seg[1] = { dec_sout_w + (size_t)i * 262144,  dsout, 262144 / 8 };
        a.seg[2] = { dec_q_w    + (size_t)i * 262144,  dq,    262144 / 8 };
        a.seg[3] = { dec_k_w    + (size_t)i * 262144,  dk,    262144 / 8 };
        a.seg[4] = { dec_v_w    + (size_t)i * 262144,  dv,    262144 / 8 };
        a.seg[5] = { dec_cout_w + (size_t)i * 262144,  dcout, 262144 / 8 };
        a.seg[6] = { dec_l1_w   + (size_t)i * 1048576, dl1,  1048576 / 8 };
        a.seg[7] = { dec_l2_w   + (size_t)i * 1048576, dl2,  1048576 / 8 };
        cvt(a);

        // causal self-attn
        gemm(T_h, dqkv, dec_qkv_b + (size_t)i * 1536, Gqkv, ND, 1536, 512, 0, true);
        transpose_v<<<dim3(2, 8, BATCH), 256, 0, stream>>>(Gqkv, VT, 1536, 1024, 128);
        attn_mfma<1><<<dim3(2, 8, BATCH), 256, 0, stream>>>(
            Gqkv, Gqkv, VT, AO_h, 128, 1536, 1536, 512, scale);
        gemm(AO_h, dsout, dec_sout_b + (size_t)i * 512, Y_h, ND, 512, 512, 0, true);
        add_ln<<<ND, 256, 0, stream>>>(T_f, Y_h,
                                       dec_n1_w + (size_t)i * 512, dec_n1_b + (size_t)i * 512,
                                       T_f, T_h);
        // cross-attn
        gemm(T_h,  dq, dec_q_b + (size_t)i * 512, Gq, ND, 512, 512, 0, true);
        gemm(Ax_h, dk, dec_k_b + (size_t)i * 512, Gk, NE, 512, 512, 0, true);
        gemm(Ax_h, dv, dec_v_b + (size_t)i * 512, Gv, NE, 512, 512, 0, true);
        transpose_v<<<dim3(8, 8, BATCH), 256, 0, stream>>>(Gv, VT, 512, 0, 512);
        attn_mfma<0><<<dim3(2, 8, BATCH), 256, 0, stream>>>(
            Gq, Gk, VT, AO_h, 512, 512, 512, 0, scale);
        gemm(AO_h, dcout, dec_cout_b + (size_t)i * 512, Y_h, ND, 512, 512, 0, true);
        add_ln<<<ND, 256, 0, stream>>>(T_f, Y_h,
                                       dec_n2_w + (size_t)i * 512, dec_n2_b + (size_t)i * 512,
                                       T_f, T_h);
        // FFN
        gemm(T_h, dl1, dec_l1_b + (size_t)i * 2048, Gh, ND, 2048, 512, 1, true);
        gemm(Gh, dl2, dec_l2_b + (size_t)i * 512, Y_h, ND, 512, 2048, 0, true);
        add_ln<<<ND, 256, 0, stream>>>(T_f, Y_h,
                                       dec_n3_w + (size_t)i * 512, dec_n3_b + (size_t)i * 512,
                                       T_f, T_h);
    }

    // ---------------- Output projection ----------------
    pad_outw<<<256, 256, 0, stream>>>(out_w, OWp);
    gemm(T_h, OWp, out_b, (float*)d_out, ND, 97, 512, 0, false);
}

// Round 4
// 1653.625 us; speedup vs baseline: 6.0150x; 1.3128x over previous
//
#include <hip/hip_runtime.h>
#include <hip/hip_bf16.h>
#include <cstddef>
#include <cstdint>

#define D_MODEL 512
#define BATCH 16
#define EPS_LN 1e-5f

typedef __bf16 bf16x8 __attribute__((ext_vector_type(8)));
typedef float f32x4 __attribute__((ext_vector_type(4)));
typedef unsigned short u16x8 __attribute__((ext_vector_type(8)));
typedef unsigned short u16x4 __attribute__((ext_vector_type(4)));
typedef unsigned short u16x2 __attribute__((ext_vector_type(2)));

__device__ __forceinline__ void gload_lds16(const void* g, void* l) {
    __builtin_amdgcn_global_load_lds(
        (const __attribute__((address_space(1))) void*)g,
        (__attribute__((address_space(3))) void*)l,
        16, 0, 0);
}

// ---------------------------------------------------------------------------
// MFMA bf16 NT GEMM: C[N,M] = act(A[N,K] @ W[M,K]^T + bias[M])
// Tile BM x 128, BK=64, 256 threads (4 waves), double-buffered LDS with
// prefetch-before-compute (2-phase). BM=128: waves 2x2 (4x4 frags);
// BM=64: waves 1x4 (4x2 frags) for small grids. Optional second bias
// (merged-weight GEMMs): c >= bsplit reads bias2[c-bsplit].
// ---------------------------------------------------------------------------
template <int BM, int OUTBF16>
__global__ __launch_bounds__(256) void gemm_mfma(
    const __bf16* __restrict__ A, const __bf16* __restrict__ W,
    const float* __restrict__ bias, const float* __restrict__ bias2,
    int bsplit, void* __restrict__ Cout, int N, int M, int K, int relu)
{
    constexpr int WC     = (BM == 128) ? 2 : 4;   // wave cols
    constexpr int WSPAN  = 128 / WC;              // cols per wave
    constexpr int NC     = WSPAN / 16;            // 4 or 2 col frags
    constexpr int ABYTES = BM * 128;
    constexpr int PA     = ABYTES / 4096;         // A staging passes
    constexpr int BUFB   = ABYTES + 16384;

    __shared__ __align__(16) char smem[2 * BUFB];

    const int tid  = threadIdx.x;
    const int lane = tid & 63;
    const int wid  = tid >> 6;
    const int wrow = (BM == 128) ? (wid >> 1) : 0;
    const int wcol = (BM == 128) ? (wid & 1) : wid;
    const int row0 = blockIdx.y * BM;
    const int col0 = blockIdx.x * 128;

    const int lrow  = lane & 15;
    const int lhalf = lane >> 4;
    const int koff0 = ((lhalf) ^ (lrow & 7)) * 16;
    const int koff1 = ((4 + lhalf) ^ (lrow & 7)) * 16;

    const int srow = tid >> 3;
    const int slot = tid & 7;
    const int sg   = slot ^ (srow & 7);

    f32x4 acc[4][NC] = {};

    const __bf16* Abase = A + (size_t)(row0 + srow) * K + sg * 8;
    const __bf16* Wbase = W + (size_t)(col0 + srow) * K + sg * 8;

    auto stage = [&](char* buf, int kt) {
#pragma unroll
        for (int p = 0; p < PA; ++p)
            gload_lds16(Abase + (size_t)p * 32 * K + kt, buf + p * 4096 + tid * 16);
#pragma unroll
        for (int p = 0; p < 4; ++p)
            gload_lds16(Wbase + (size_t)p * 32 * K + kt,
                        buf + ABYTES + p * 4096 + tid * 16);
    };

    stage(smem, 0);
    const int nkt = K >> 6;
    int cur = 0;
    for (int kt = 0; kt < nkt; ++kt) {
        __syncthreads();                 // staged buf[cur] ready
        if (kt + 1 < nkt) stage(smem + (cur ^ 1) * BUFB, (kt + 1) * 64);
        const char* aB = smem + cur * BUFB + (wrow * 64 + lrow) * 128;
        const char* wB = smem + cur * BUFB + ABYTES + (wcol * WSPAN + lrow) * 128;
#pragma unroll
        for (int ks = 0; ks < 2; ++ks) {
            const int ko = ks ? koff1 : koff0;
            bf16x8 af[4], bfr[NC];
#pragma unroll
            for (int m = 0; m < 4; ++m) af[m]  = *(const bf16x8*)(aB + m * 2048 + ko);
#pragma unroll
            for (int n = 0; n < NC; ++n) bfr[n] = *(const bf16x8*)(wB + n * 2048 + ko);
#pragma unroll
            for (int m = 0; m < 4; ++m)
#pragma unroll
                for (int n = 0; n < NC; ++n)
                    acc[m][n] = __builtin_amdgcn_mfma_f32_16x16x32_bf16(
                        af[m], bfr[n], acc[m][n], 0, 0, 0);
        }
        cur ^= 1;
    }

    const int orow = row0 + wrow * 64 + lhalf * 4;
    const int ocol = col0 + wcol * WSPAN + lrow;
#pragma unroll
    for (int n = 0; n < NC; ++n) {
        const int c = ocol + n * 16;
        if (c < M) {
            const float bv = (bias2 && c >= bsplit) ? bias2[c - bsplit] : bias[c];
#pragma unroll
            for (int m = 0; m < 4; ++m) {
#pragma unroll
                for (int j = 0; j < 4; ++j) {
                    const int r = orow + m * 16 + j;
                    float v = acc[m][n][j] + bv;
                    if (relu) v = fmaxf(v, 0.f);
                    if (OUTBF16) ((__bf16*)Cout)[(size_t)r * M + c] = (__bf16)v;
                    else         ((float*)Cout)[(size_t)r * M + c] = v;
                }
            }
        }
    }
}

// ---------------------------------------------------------------------------
// V transpose: V[(s*B+b)*stride + voff + h*64 + d] (bf16) ->
//              VT[((b*8+h)*64 + d)*S + s] (bf16).  grid (S/64, 8, 16).
// ---------------------------------------------------------------------------
__global__ __launch_bounds__(256) void transpose_v(
    const __bf16* __restrict__ V, __bf16* __restrict__ VT,
    int stride, int voff, int S)
{
    __shared__ __align__(16) char smem[8192];
    const int tid = threadIdx.x;
    const int kc = blockIdx.x, h = blockIdx.y, b = blockIdx.z;
    const int srow = tid >> 3, slot = tid & 7;
#pragma unroll
    for (int p = 0; p < 2; ++p) {
        int r = p * 32 + srow;
        const __bf16* src = V + ((size_t)(kc * 64 + r) * BATCH + b) * stride
                              + voff + h * 64 + slot * 8;
        gload_lds16(src, smem + (p * 256 + tid) * 16);
    }
    __syncthreads();
    const int l = tid & 63, w = tid >> 6;
    const int d2 = w * 8 + (l >> 3);
    const int s0 = (l & 7) * 8;
    unsigned rows[8];
#pragma unroll
    for (int e = 0; e < 8; ++e)
        rows[e] = *(const unsigned*)(smem + (s0 + e) * 128 + d2 * 4);
    union { __bf16 h8[8]; u16x8 u; } r0, r1;
#pragma unroll
    for (int e = 0; e < 8; ++e) {
        r0.h8[e] = ((const __bf16*)&rows[e])[0];
        r1.h8[e] = ((const __bf16*)&rows[e])[1];
    }
    size_t obase = ((size_t)(b * 8 + h) * 64 + d2 * 2) * S + kc * 64 + s0;
    *(u16x8*)(VT + obase)     = r0.u;
    *(u16x8*)(VT + obase + S) = r1.u;
}

// ---------------------------------------------------------------------------
// MFMA flash attention, double-buffered K/V staging.
// Block = 64 q-rows (4 waves x 16), 64-key chunks. grid (Sq/64, 8, 16).
// ---------------------------------------------------------------------------
template <int CAUSAL>
__global__ __launch_bounds__(256) void attn_mfma(
    const __bf16* __restrict__ Qb, const __bf16* __restrict__ Kb,
    const __bf16* __restrict__ VT, __bf16* __restrict__ Op,
    int Skv, int qstride, int kstride, int koff, float scale)
{
    __shared__ __align__(16) char smem[40960];   // 2x(K 8K + V 8K) + 4x2K P
    const int tid = threadIdx.x;
    const int l   = tid & 63;
    const int w   = tid >> 6;
    char* Psm = smem + 32768 + w * 2048;

    const int qc = blockIdx.x;
    const int h  = blockIdx.y;
    const int b  = blockIdx.z;
    const int l15 = l & 15;
    const int g   = l >> 4;
    const int sw  = l15 & 7;

    const int sq = qc * 64 + w * 16 + l15;
    const __bf16* qrow = Qb + ((size_t)sq * BATCH + b) * qstride + h * 64 + g * 8;
    const bf16x8 qf0 = *(const bf16x8*)(qrow);
    const bf16x8 qf1 = *(const bf16x8*)(qrow + 32);

    const int srow = tid >> 3;
    const int slot = tid & 7;

    auto stageKV = [&](char* buf, int kc) {
#pragma unroll
        for (int p = 0; p < 2; ++p) {
            const int r   = p * 32 + srow;
            const int sgo = (slot ^ (r & 7)) * 8;
            const __bf16* ksrc = Kb + ((size_t)(kc * 64 + r) * BATCH + b) * kstride
                                    + koff + h * 64 + sgo;
            gload_lds16(ksrc, buf + (p * 256 + tid) * 16);
            const __bf16* vsrc = VT + ((size_t)((b * 8 + h) * 64 + r)) * Skv
                                    + kc * 64 + sgo;
            gload_lds16(vsrc, buf + 8192 + (p * 256 + tid) * 16);
        }
    };

    f32x4 acc[4] = {};
    float m_run = -1e30f, l_run = 0.f;

    const int nkc = CAUSAL ? (qc + 1) : (Skv >> 6);
    stageKV(smem, 0);
    int cur = 0;
    for (int kc = 0; kc < nkc; ++kc) {
        __syncthreads();                 // buf[cur] staged + prev reads done
        if (kc + 1 < nkc) stageKV(smem + (cur ^ 1) * 16384, kc + 1);
        const char* Ksm = smem + cur * 16384;
        const char* Vsm = Ksm + 8192;

        // QK^T (swapped): st[f] = S^T[key = f*16+4g+j][q = l15]
        f32x4 st[4];
#pragma unroll
        for (int f = 0; f < 4; ++f) {
            const char* kr = Ksm + (f * 16 + l15) * 128;
            bf16x8 ka0 = *(const bf16x8*)(kr + ((g ^ sw) * 16));
            bf16x8 ka1 = *(const bf16x8*)(kr + (((4 + g) ^ sw) * 16));
            f32x4 z = {};
            z = __builtin_amdgcn_mfma_f32_16x16x32_bf16(ka0, qf0, z, 0, 0, 0);
            st[f] = __builtin_amdgcn_mfma_f32_16x16x32_bf16(ka1, qf1, z, 0, 0, 0);
        }

        // scale + mask + online softmax (lane owns q = l15)
        float rmax = -1e30f;
#pragma unroll
        for (int f = 0; f < 4; ++f)
#pragma unroll
            for (int j = 0; j < 4; ++j) {
                float v = st[f][j] * scale;
                if (CAUSAL) {
                    if (kc * 64 + f * 16 + g * 4 + j > sq) v = -1e30f;
                }
                st[f][j] = v;
                rmax = fmaxf(rmax, v);
            }
        rmax = fmaxf(rmax, __shfl_xor(rmax, 16, 64));
        rmax = fmaxf(rmax, __shfl_xor(rmax, 32, 64));
        const float mn = fmaxf(m_run, rmax);
        const float corr = __expf(m_run - mn);
        m_run = mn;
        float rsum = 0.f;
#pragma unroll
        for (int f = 0; f < 4; ++f)
#pragma unroll
            for (int j = 0; j < 4; ++j) {
                float p = __expf(st[f][j] - mn);
                st[f][j] = p;
                rsum += p;
            }
        rsum += __shfl_xor(rsum, 16, 64);
        rsum += __shfl_xor(rsum, 32, 64);
        l_run = l_run * corr + rsum;

#pragma unroll
        for (int j = 0; j < 4; ++j) {
            const float cj = __shfl(corr, g * 20 + j, 64);
            acc[0][j] *= cj; acc[1][j] *= cj; acc[2][j] *= cj; acc[3][j] *= cj;
        }

        // pack P -> bf16 into wave-private swizzled LDS [16 q][64 key]
#pragma unroll
        for (int f = 0; f < 4; ++f)
#pragma unroll
            for (int j2 = 0; j2 < 2; ++j2) {
                union { __bf16 h2[2]; unsigned u; } cv;
                cv.h2[0] = (__bf16)st[f][2 * j2];
                cv.h2[1] = (__bf16)st[f][2 * j2 + 1];
                const int key0 = 16 * f + 4 * g + 2 * j2;
                const int byte = l15 * 128 + (((key0 >> 3) ^ sw) * 16) + (key0 & 7) * 2;
                *(unsigned*)(Psm + byte) = cv.u;
            }

        // PV: acc[n] += P x VT (wave-private P, no barrier)
#pragma unroll
        for (int ks = 0; ks < 2; ++ks) {
            const int so = ((4 * ks + g) ^ sw) * 16;
            bf16x8 pa = *(const bf16x8*)(Psm + l15 * 128 + so);
#pragma unroll
            for (int n = 0; n < 4; ++n) {
                bf16x8 vb = *(const bf16x8*)(Vsm + (n * 16 + l15) * 128 + so);
                acc[n] = __builtin_amdgcn_mfma_f32_16x16x32_bf16(pa, vb, acc[n], 0, 0, 0);
            }
        }
        cur ^= 1;
    }

    const float inv = 1.f / l_run;
#pragma unroll
    for (int j = 0; j < 4; ++j) {
        const float ij = __shfl(inv, g * 20 + j, 64);
        const int s = qc * 64 + w * 16 + g * 4 + j;
        __bf16* orow = Op + ((size_t)s * BATCH + b) * D_MODEL + h * 64 + l15;
#pragma unroll
        for (int n = 0; n < 4; ++n)
            orow[n * 16] = (__bf16)(acc[n][j] * ij);
    }
}

// ---------------------------------------------------------------------------
// Residual add + LayerNorm: X fp32 + Y bf16 -> fp32 + bf16. One block/token.
// ---------------------------------------------------------------------------
__global__ __launch_bounds__(256) void add_ln(
    const float* __restrict__ X, const __bf16* __restrict__ Y,
    const float* __restrict__ w, const float* __restrict__ bias,
    float* __restrict__ Of, __bf16* __restrict__ Oh)
{
    const int t   = blockIdx.x;
    const int tid = threadIdx.x;
    const float2 x2 = *(const float2*)(X + (size_t)t * D_MODEL + tid * 2);
    const u16x2 yv = *(const u16x2*)(Y + (size_t)t * D_MODEL + tid * 2);
    union { u16x2 u; __bf16 h2[2]; } yc; yc.u = yv;
    float v0 = x2.x + (float)yc.h2[0], v1 = x2.y + (float)yc.h2[1];
    float sum = v0 + v1;
    float sq  = v0 * v0 + v1 * v1;
#pragma unroll
    for (int off = 32; off; off >>= 1) {
        sum += __shfl_xor(sum, off);
        sq  += __shfl_xor(sq, off);
    }
    __shared__ float ssum[4], ssq[4];
    const int wid = tid >> 6;
    if ((tid & 63) == 0) { ssum[wid] = sum; ssq[wid] = sq; }
    __syncthreads();
    sum = ssum[0] + ssum[1] + ssum[2] + ssum[3];
    sq  = ssq[0] + ssq[1] + ssq[2] + ssq[3];

    const float mu  = sum * (1.f / D_MODEL);
    const float var = sq * (1.f / D_MODEL) - mu * mu;
    const float rs  = rsqrtf(var + EPS_LN);
    const float2 w2 = *(const float2*)(w + tid * 2);
    const float2 b2 = *(const float2*)(bias + tid * 2);
    float o0 = (v0 - mu) * rs * w2.x + b2.x;
    float o1 = (v1 - mu) * rs * w2.y + b2.y;
    *(float2*)(Of + (size_t)t * D_MODEL + tid * 2) = make_float2(o0, o1);
    union { __bf16 h2[2]; u16x2 u; } cv;
    cv.h2[0] = (__bf16)o0; cv.h2[1] = (__bf16)o1;
    *(u16x2*)(Oh + (size_t)t * D_MODEL + tid * 2) = cv.u;
}

// ---------------------------------------------------------------------------
// Token embedding + positional encoding, dual output. One block per (s,b).
// ---------------------------------------------------------------------------
__global__ __launch_bounds__(256) void embed_pos(
    const int* __restrict__ tokens, const float* __restrict__ emb,
    float* __restrict__ Of, __bf16* __restrict__ Oh)
{
    const int t   = blockIdx.x;
    const int s   = t / BATCH;
    const int tid = threadIdx.x;
    const int tok = tokens[t];
    const float C = 9.210340371976184f / 256.f;
    const int d = tid * 2;
    const int j = (d < 256) ? d : (d - 256);
    float a0 = (float)s * expf(-(float)j * C);
    float a1 = (float)s * expf(-(float)(j + 1) * C);
    float pe0 = (d < 256) ? sinf(a0) : cosf(a0);
    float pe1 = (d < 256) ? sinf(a1) : cosf(a1);
    const float2 e2 = *(const float2*)(emb + (size_t)tok * D_MODEL + d);
    float o0 = e2.x + pe0, o1 = e2.y + pe1;
    *(float2*)(Of + (size_t)t * D_MODEL + d) = make_float2(o0, o1);
    union { __bf16 h2[2]; u16x2 u; } cv;
    cv.h2[0] = (__bf16)o0; cv.h2[1] = (__bf16)o1;
    *(u16x2*)(Oh + (size_t)t * D_MODEL + d) = cv.u;
}

// ---------------------------------------------------------------------------
// Multi-segment fp32 -> bf16 conversion.
// ---------------------------------------------------------------------------
struct CvtSeg { const float* s; __bf16* d; int n8; };
struct CvtArgs { CvtSeg seg[8]; int tot8; };

__global__ __launch_bounds__(256) void cvt_multi(CvtArgs a)
{
    const int stride = gridDim.x * 256;
    for (int u = blockIdx.x * 256 + threadIdx.x; u < a.tot8; u += stride) {
        int v = u;
        for (int sgi = 0; sgi < 8; ++sgi) {
            const int n8 = a.seg[sgi].n8;
            if (v < n8) {
                const float4 f0 = ((const float4*)a.seg[sgi].s)[v * 2];
                const float4 f1 = ((const float4*)a.seg[sgi].s)[v * 2 + 1];
                union { __bf16 h[8]; u16x8 u; } c;
                c.h[0] = (__bf16)f0.x; c.h[1] = (__bf16)f0.y;
                c.h[2] = (__bf16)f0.z; c.h[3] = (__bf16)f0.w;
                c.h[4] = (__bf16)f1.x; c.h[5] = (__bf16)f1.y;
                c.h[6] = (__bf16)f1.z; c.h[7] = (__bf16)f1.w;
                ((u16x8*)a.seg[sgi].d)[v] = c.u;
                break;
            }
            v -= n8;
        }
    }
}

__global__ __launch_bounds__(256) void pad_outw(
    const float* __restrict__ w, __bf16* __restrict__ o)
{
    const int idx = blockIdx.x * 256 + threadIdx.x;
    const int r = idx >> 9;
    const int c = idx & 511;
    o[idx] = (__bf16)(r < 97 ? w[r * 512 + c] : 0.f);
}

// ---------------------------------------------------------------------------
// Host orchestration
// ---------------------------------------------------------------------------
extern "C" void kernel_launch(void* const* d_in, const int* in_sizes, int n_in,
                              void* d_out, int out_size, void* d_ws, size_t ws_size,
                              hipStream_t stream)
{
    const float* src     = (const float*)d_in[0];
    const int*   tokens  = (const int*)d_in[1];
    const float* tok_emb = (const float*)d_in[2];
    const float* enc_qkv_w = (const float*)d_in[3];
    const float* enc_qkv_b = (const float*)d_in[4];
    const float* enc_out_w = (const float*)d_in[5];
    const float* enc_out_b = (const float*)d_in[6];
    const float* enc_l1_w  = (const float*)d_in[7];
    const float* enc_l1_b  = (const float*)d_in[8];
    const float* enc_l2_w  = (const float*)d_in[9];
    const float* enc_l2_b  = (const float*)d_in[10];
    const float* enc_n1_w  = (const float*)d_in[11];
    const float* enc_n1_b  = (const float*)d_in[12];
    const float* enc_n2_w  = (const float*)d_in[13];
    const float* enc_n2_b  = (const float*)d_in[14];
    const float* dec_qkv_w = (const float*)d_in[15];
    const float* dec_qkv_b = (const float*)d_in[16];
    const float* dec_sout_w = (const float*)d_in[17];
    const float* dec_sout_b = (const float*)d_in[18];
    const float* dec_q_w   = (const float*)d_in[19];
    const float* dec_q_b   = (const float*)d_in[20];
    const float* dec_k_w   = (const float*)d_in[21];
    const float* dec_k_b   = (const float*)d_in[22];
    const float* dec_v_w   = (const float*)d_in[23];
    const float* dec_v_b   = (const float*)d_in[24];
    const float* dec_cout_w = (const float*)d_in[25];
    const float* dec_cout_b = (const float*)d_in[26];
    const float* dec_l1_w  = (const float*)d_in[27];
    const float* dec_l1_b  = (const float*)d_in[28];
    const float* dec_l2_w  = (const float*)d_in[29];
    const float* dec_l2_b  = (const float*)d_in[30];
    const float* dec_n1_w  = (const float*)d_in[31];
    const float* dec_n1_b  = (const float*)d_in[32];
    const float* dec_n2_w  = (const float*)d_in[33];
    const float* dec_n2_b  = (const float*)d_in[34];
    const float* dec_n3_w  = (const float*)d_in[35];
    const float* dec_n3_b  = (const float*)d_in[36];
    const float* out_w     = (const float*)d_in[37];
    const float* out_b     = (const float*)d_in[38];

    const int NE = 512 * BATCH;   // 8192
    const int ND = 128 * BATCH;   // 2048
    const float scale = 0.125f;

    // -------- workspace layout (99,745,792 bytes total) --------
    char* w8 = (char*)d_ws;
    float*  Ax_f = (float*) (w8 + 0);          // 16 MB enc residual fp32
    float*  T_f  = (float*) (w8 + 16777216);   //  4 MB dec residual fp32
    __bf16* Ax_h = (__bf16*)(w8 + 20971520);   //  8 MB enc bf16
    __bf16* T_h  = (__bf16*)(w8 + 29360128);   //  2 MB dec bf16
    __bf16* AO_h = (__bf16*)(w8 + 31457280);   //  8 MB attn out bf16
    __bf16* Wk   = (__bf16*)(w8 + 39845888);   //  9 MB weight scratch
    __bf16* OWp  = (__bf16*)(w8 + 49283072);   //  0.13 MB padded out_w
    __bf16* VT   = (__bf16*)(w8 + 49414144);   //  8 MB V-transpose
    char*   Gb   = w8 + 57802752;              // 33.5 MB union
    __bf16* Gqkv = (__bf16*)Gb;                // qkv bf16 [N][1536]
    __bf16* Gh   = (__bf16*)Gb;                // ffn hidden bf16 [N][2048]
    __bf16* Gq   = (__bf16*)Gb;                // cross q bf16 [2048][512]
    __bf16* Gkv  = (__bf16*)(Gb + 2097152);    // cross kv bf16 [8192][1024]
    __bf16* Y_h  = (__bf16*)(w8 + 91357184);   //  8 MB residual-Y bf16

    auto gemm = [&](const __bf16* Am, const __bf16* Wm, const float* bv,
                    const float* bv2, int bsplit, void* C,
                    int N, int M, int K, int relu, bool outbf) {
        const int nb128 = ((M + 127) / 128) * (N / 128);
        if (nb128 >= 256) {
            dim3 grid((M + 127) / 128, N / 128);
            if (outbf) gemm_mfma<128, 1><<<grid, 256, 0, stream>>>(Am, Wm, bv, bv2, bsplit, C, N, M, K, relu);
            else       gemm_mfma<128, 0><<<grid, 256, 0, stream>>>(Am, Wm, bv, bv2, bsplit, C, N, M, K, relu);
        } else {
            dim3 grid((M + 127) / 128, N / 64);
            if (outbf) gemm_mfma<64, 1><<<grid, 256, 0, stream>>>(Am, Wm, bv, bv2, bsplit, C, N, M, K, relu);
            else       gemm_mfma<64, 0><<<grid, 256, 0, stream>>>(Am, Wm, bv, bv2, bsplit, C, N, M, K, relu);
        }
    };
    auto cvt = [&](CvtArgs& a) {
        int tot = 0;
        for (int i = 0; i < 8; ++i) tot += a.seg[i].n8;
        a.tot8 = tot;
        cvt_multi<<<1024, 256, 0, stream>>>(a);
    };

    { CvtArgs a = {}; a.seg[0] = { src, Ax_h, NE * 512 / 8 }; cvt(a); }

    // ---------------- Encoder ----------------
    __bf16* wqkv = Wk;
    __bf16* wout = Wk + 786432;
    __bf16* wl1  = Wk + 1048576;
    __bf16* wl2  = Wk + 2097152;
    for (int i = 0; i < 6; ++i) {
        CvtArgs a = {};
        a.seg[0] = { enc_qkv_w + (size_t)i * 786432,  wqkv, 786432 / 8 };
        a.seg[1] = { enc_out_w + (size_t)i * 262144,  wout, 262144 / 8 };
        a.seg[2] = { enc_l1_w  + (size_t)i * 1048576, wl1, 1048576 / 8 };
        a.seg[3] = { enc_l2_w  + (size_t)i * 1048576, wl2, 1048576 / 8 };
        cvt(a);

        gemm(Ax_h, wqkv, enc_qkv_b + (size_t)i * 1536, nullptr, 0, Gqkv, NE, 1536, 512, 0, true);
        transpose_v<<<dim3(8, 8, BATCH), 256, 0, stream>>>(Gqkv, VT, 1536, 1024, 512);
        attn_mfma<0><<<dim3(8, 8, BATCH), 256, 0, stream>>>(
            Gqkv, Gqkv, VT, AO_h, 512, 1536, 1536, 512, scale);
        gemm(AO_h, wout, enc_out_b + (size_t)i * 512, nullptr, 0, Y_h, NE, 512, 512, 0, true);
        add_ln<<<NE, 256, 0, stream>>>((i == 0) ? src : Ax_f, Y_h,
                                       enc_n1_w + (size_t)i * 512, enc_n1_b + (size_t)i * 512,
                                       Ax_f, Ax_h);
        gemm(Ax_h, wl1, enc_l1_b + (size_t)i * 2048, nullptr, 0, Gh, NE, 2048, 512, 1, true);
        gemm(Gh, wl2, enc_l2_b + (size_t)i * 512, nullptr, 0, Y_h, NE, 512, 2048, 0, true);
        add_ln<<<NE, 256, 0, stream>>>(Ax_f, Y_h,
                                       enc_n2_w + (size_t)i * 512, enc_n2_b + (size_t)i * 512,
                                       Ax_f, Ax_h);
    }

    // ---------------- Decoder ----------------
    embed_pos<<<ND, 256, 0, stream>>>(tokens, tok_emb, T_f, T_h);
    __bf16* dqkv = Wk;
    __bf16* dsout = Wk + 786432;
    __bf16* dq   = Wk + 1048576;
    __bf16* dkv  = Wk + 1310720;      // k rows [0,512) then v rows [512,1024)
    __bf16* dcout = Wk + 1835008;
    __bf16* dl1  = Wk + 2097152;
    __bf16* dl2  = Wk + 3145728;
    for (int i = 0; i < 6; ++i) {
        CvtArgs a = {};
        a.seg[0] = { dec_qkv_w  + (size_t)i * 786432,  dqkv,  786432 / 8 };
        a.seg[1] = { dec_sout_w + (size_t)i * 262144,  dsout, 262144 / 8 };
        a.seg[2] = { dec_q_w    + (size_t)i * 262144,  dq,    262144 / 8 };
        a.seg[3] = { dec_k_w    + (size_t)i * 262144,  dkv,   262144 / 8 };
        a.seg[4] = { dec_v_w    + (size_t)i * 262144,  dkv + 262144, 262144 / 8 };
        a.seg[5] = { dec_cout_w + (size_t)i * 262144,  dcout, 262144 / 8 };
        a.seg[6] = { dec_l1_w   + (size_t)i * 1048576, dl1,  1048576 / 8 };
        a.seg[7] = { dec_l2_w   + (size_t)i * 1048576, dl2,  1048576 / 8 };
        cvt(a);

        // causal self-attn
        gemm(T_h, dqkv, dec_qkv_b + (size_t)i * 1536, nullptr, 0, Gqkv, ND, 1536, 512, 0, true);
        transpose_v<<<dim3(2, 8, BATCH), 256, 0, stream>>>(Gqkv, VT, 1536, 1024, 128);
        attn_mfma<1><<<dim3(2, 8, BATCH), 256, 0, stream>>>(
            Gqkv, Gqkv, VT, AO_h, 128, 1536, 1536, 512, scale);
        gemm(AO_h, dsout, dec_sout_b + (size_t)i * 512, nullptr, 0, Y_h, ND, 512, 512, 0, true);
        add_ln<<<ND, 256, 0, stream>>>(T_f, Y_h,
                                       dec_n1_w + (size_t)i * 512, dec_n1_b + (size_t)i * 512,
                                       T_f, T_h);
        // cross-attn (merged K+V GEMM, M=1024, dual bias)
        gemm(T_h,  dq, dec_q_b + (size_t)i * 512, nullptr, 0, Gq, ND, 512, 512, 0, true);
        gemm(Ax_h, dkv, dec_k_b + (size_t)i * 512, dec_v_b + (size_t)i * 512, 512,
             Gkv, NE, 1024, 512, 0, true);
        transpose_v<<<dim3(8, 8, BATCH), 256, 0, stream>>>(Gkv, VT, 1024, 512, 512);
        attn_mfma<0><<<dim3(2, 8, BATCH), 256, 0, stream>>>(
            Gq, Gkv, VT, AO_h, 512, 512, 1024, 0, scale);
        gemm(AO_h, dcout, dec_cout_b + (size_t)i * 512, nullptr, 0, Y_h, ND, 512, 512, 0, true);
        add_ln<<<ND, 256, 0, stream>>>(T_f, Y_h,
                                       dec_n2_w + (size_t)i * 512, dec_n2_b + (size_t)i * 512,
                                       T_f, T_h);
        // FFN
        gemm(T_h, dl1, dec_l1_b + (size_t)i * 2048, nullptr, 0, Gh, ND, 2048, 512, 1, true);
        gemm(Gh, dl2, dec_l2_b + (size_t)i * 512, nullptr, 0, Y_h, ND, 512, 2048, 0, true);
        add_ln<<<ND, 256, 0, stream>>>(T_f, Y_h,
                                       dec_n3_w + (size_t)i * 512, dec_n3_b + (size_t)i * 512,
                                       T_f, T_h);
    }

    // ---------------- Output projection ----------------
    pad_outw<<<256, 256, 0, stream>>>(out_w, OWp);
    gemm(T_h, OWp, out_b, nullptr, 0, (float*)d_out, ND, 97, 512, 0, false);
}

// Round 5
// 1651.507 us; speedup vs baseline: 6.0227x; 1.0013x over previous
//
#include <hip/hip_runtime.h>
#include <hip/hip_bf16.h>
#include <cstddef>
#include <cstdint>

#define D_MODEL 512
#define BATCH 16
#define EPS_LN 1e-5f

typedef __bf16 bf16x8 __attribute__((ext_vector_type(8)));
typedef float f32x4 __attribute__((ext_vector_type(4)));
typedef unsigned short u16x8 __attribute__((ext_vector_type(8)));
typedef unsigned short u16x4 __attribute__((ext_vector_type(4)));
typedef unsigned short u16x2 __attribute__((ext_vector_type(2)));

__device__ __forceinline__ void gload_lds16(const void* g, void* l) {
    __builtin_amdgcn_global_load_lds(
        (const __attribute__((address_space(1))) void*)g,
        (__attribute__((address_space(3))) void*)l,
        16, 0, 0);
}

// ---------------------------------------------------------------------------
// MFMA bf16 NT GEMM, activations laid out [b][s][*] (row r = b*S + s).
//   C[r, c] = act(A[r,:] . Wrow[c,:] + bias[c])
// Tile BM x 128, BK=64, 256 thr (4 waves), double-buffered 2-phase LDS.
// SWAP=1: swapped-operand epilogue -> 4 consecutive cols/lane-reg, vector
//         stores (bf16 out, full tiles, no VT/perm).
// SWAP=0: classic layout; supports: col guard (c < Mlim), VT side-output for
//         cols >= m_vt0 (VT[((b*8+h)*64+d)<<log2S | s], u16x4), dual bias
//         (c >= bsplit -> bias2), W split (c >= wsplit -> W2), row permute
//         on store (permrow: r=b*S+s -> s*BATCH+b).
// ---------------------------------------------------------------------------
template <int BM, int OUTBF16, int SWAP>
__global__ __launch_bounds__(256) void gemm_mfma(
    const __bf16* __restrict__ A, const __bf16* __restrict__ W,
    const __bf16* __restrict__ W2, int wsplit,
    const float* __restrict__ bias, const float* __restrict__ bias2, int bsplit,
    void* __restrict__ Cout, __bf16* __restrict__ VTout, int m_vt0, int log2S,
    int N, int Mlim, int MS, int K, int relu, int permrow)
{
    constexpr int WC     = (BM == 128) ? 2 : 4;
    constexpr int WSPAN  = 128 / WC;
    constexpr int NC     = WSPAN / 16;
    constexpr int ABYTES = BM * 128;
    constexpr int PA     = ABYTES / 4096;
    constexpr int BUFB   = ABYTES + 16384;

    __shared__ __align__(16) char smem[2 * BUFB];

    const int tid  = threadIdx.x;
    const int lane = tid & 63;
    const int wid  = tid >> 6;
    const int wrow = (BM == 128) ? (wid >> 1) : 0;
    const int wcol = (BM == 128) ? (wid & 1) : wid;
    const int row0 = blockIdx.y * BM;
    const int col0 = blockIdx.x * 128;

    const int lrow  = lane & 15;
    const int lhalf = lane >> 4;
    const int koff0 = ((lhalf) ^ (lrow & 7)) * 16;
    const int koff1 = ((4 + lhalf) ^ (lrow & 7)) * 16;

    const int srow = tid >> 3;
    const int slot = tid & 7;
    const int sg   = slot ^ (srow & 7);

    f32x4 acc[4][NC] = {};

    const __bf16* Wsel = W;
    int wc0 = col0;
    if (col0 >= wsplit) { Wsel = W2; wc0 = col0 - wsplit; }

    const __bf16* Abase = A + (size_t)(row0 + srow) * K + sg * 8;
    const __bf16* Wbase = Wsel + (size_t)(wc0 + srow) * K + sg * 8;

    auto stage = [&](char* buf, int kt) {
#pragma unroll
        for (int p = 0; p < PA; ++p)
            gload_lds16(Abase + (size_t)p * 32 * K + kt, buf + p * 4096 + tid * 16);
#pragma unroll
        for (int p = 0; p < 4; ++p)
            gload_lds16(Wbase + (size_t)p * 32 * K + kt,
                        buf + ABYTES + p * 4096 + tid * 16);
    };

    stage(smem, 0);
    const int nkt = K >> 6;
    int cur = 0;
    for (int kt = 0; kt < nkt; ++kt) {
        __syncthreads();
        if (kt + 1 < nkt) stage(smem + (cur ^ 1) * BUFB, (kt + 1) * 64);
        const char* aB = smem + cur * BUFB + (wrow * 64 + lrow) * 128;
        const char* wB = smem + cur * BUFB + ABYTES + (wcol * WSPAN + lrow) * 128;
#pragma unroll
        for (int ks = 0; ks < 2; ++ks) {
            const int ko = ks ? koff1 : koff0;
            bf16x8 af[4], bfr[NC];
#pragma unroll
            for (int m = 0; m < 4; ++m) af[m]  = *(const bf16x8*)(aB + m * 2048 + ko);
#pragma unroll
            for (int n = 0; n < NC; ++n) bfr[n] = *(const bf16x8*)(wB + n * 2048 + ko);
            if (SWAP) {
#pragma unroll
                for (int m = 0; m < 4; ++m)
#pragma unroll
                    for (int n = 0; n < NC; ++n)
                        acc[m][n] = __builtin_amdgcn_mfma_f32_16x16x32_bf16(
                            bfr[n], af[m], acc[m][n], 0, 0, 0);
            } else {
#pragma unroll
                for (int m = 0; m < 4; ++m)
#pragma unroll
                    for (int n = 0; n < NC; ++n)
                        acc[m][n] = __builtin_amdgcn_mfma_f32_16x16x32_bf16(
                            af[m], bfr[n], acc[m][n], 0, 0, 0);
            }
        }
        cur ^= 1;
    }

    if (SWAP) {
        // D^T layout: lane owns row r = ...+m*16+l15; 4 consecutive cols per reg
#pragma unroll
        for (int m = 0; m < 4; ++m) {
            const int r = row0 + wrow * 64 + m * 16 + lrow;
#pragma unroll
            for (int n = 0; n < NC; ++n) {
                const int c0 = col0 + wcol * WSPAN + n * 16 + lhalf * 4;
                const float4 bv = *(const float4*)(bias + c0);
                float o0 = acc[m][n][0] + bv.x, o1 = acc[m][n][1] + bv.y;
                float o2 = acc[m][n][2] + bv.z, o3 = acc[m][n][3] + bv.w;
                if (relu) {
                    o0 = fmaxf(o0, 0.f); o1 = fmaxf(o1, 0.f);
                    o2 = fmaxf(o2, 0.f); o3 = fmaxf(o3, 0.f);
                }
                if (OUTBF16) {
                    union { __bf16 h4[4]; u16x4 u; } pk;
                    pk.h4[0] = (__bf16)o0; pk.h4[1] = (__bf16)o1;
                    pk.h4[2] = (__bf16)o2; pk.h4[3] = (__bf16)o3;
                    *(u16x4*)((__bf16*)Cout + (size_t)r * MS + c0) = pk.u;
                } else {
                    *(float4*)((float*)Cout + (size_t)r * MS + c0) =
                        make_float4(o0, o1, o2, o3);
                }
            }
        }
    } else {
        const int orow = row0 + wrow * 64 + lhalf * 4;
        const int ocol = col0 + wcol * WSPAN + lrow;
        const int smask = (1 << log2S) - 1;
#pragma unroll
        for (int n = 0; n < NC; ++n) {
            const int c = ocol + n * 16;
            if (c >= m_vt0) {
                // V^T side output (coalesced along s)
                const int cv = c - m_vt0;
                const int hh = cv >> 6, dd = cv & 63;
                const float bv = (bias2 && c >= bsplit) ? bias2[c - bsplit] : bias[c];
#pragma unroll
                for (int m = 0; m < 4; ++m) {
                    const int rr = orow + m * 16;
                    const int bb = rr >> log2S, ss = rr & smask;
                    union { __bf16 h4[4]; u16x4 u; } pk;
#pragma unroll
                    for (int j = 0; j < 4; ++j)
                        pk.h4[j] = (__bf16)(acc[m][n][j] + bv);
                    *(u16x4*)(VTout + (((size_t)((bb * 8 + hh) * 64 + dd)) << log2S) + ss) = pk.u;
                }
            } else if (c < Mlim) {
                const float bv = (bias2 && c >= bsplit) ? bias2[c - bsplit] : bias[c];
#pragma unroll
                for (int m = 0; m < 4; ++m) {
#pragma unroll
                    for (int j = 0; j < 4; ++j) {
                        int rr = orow + m * 16 + j;
                        if (permrow) rr = ((rr & smask) * BATCH) + (rr >> log2S);
                        float v = acc[m][n][j] + bv;
                        if (relu) v = fmaxf(v, 0.f);
                        if (OUTBF16) ((__bf16*)Cout)[(size_t)rr * MS + c] = (__bf16)v;
                        else         ((float*)Cout)[(size_t)rr * MS + c] = v;
                    }
                }
            }
        }
    }
}

// ---------------------------------------------------------------------------
// MFMA flash attention, [b][s][*] layout, double-buffered K/V staging.
// Block = 64 q-rows (4 waves x 16), 64-key chunks. grid (Sq/64, 8, 16).
// VT: [((b*8+h)*64+d)][Skv].
// ---------------------------------------------------------------------------
template <int CAUSAL>
__global__ __launch_bounds__(256) void attn_mfma(
    const __bf16* __restrict__ Qb, const __bf16* __restrict__ Kb,
    const __bf16* __restrict__ VT, __bf16* __restrict__ Op,
    int Sq, int Skv, int qstride, int kstride, int koff, float scale)
{
    __shared__ __align__(16) char smem[40960];
    const int tid = threadIdx.x;
    const int l   = tid & 63;
    const int w   = tid >> 6;
    char* Psm = smem + 32768 + w * 2048;

    const int qc = blockIdx.x;
    const int h  = blockIdx.y;
    const int b  = blockIdx.z;
    const int l15 = l & 15;
    const int g   = l >> 4;
    const int sw  = l15 & 7;

    const int sq = qc * 64 + w * 16 + l15;   // s index of this lane's q row
    const __bf16* qrow = Qb + ((size_t)(b * Sq + sq)) * qstride + h * 64 + g * 8;
    const bf16x8 qf0 = *(const bf16x8*)(qrow);
    const bf16x8 qf1 = *(const bf16x8*)(qrow + 32);

    const int srow = tid >> 3;
    const int slot = tid & 7;

    auto stageKV = [&](char* buf, int kc) {
#pragma unroll
        for (int p = 0; p < 2; ++p) {
            const int r   = p * 32 + srow;
            const int sgo = (slot ^ (r & 7)) * 8;
            const __bf16* ksrc = Kb + ((size_t)(b * Skv + kc * 64 + r)) * kstride
                                    + koff + h * 64 + sgo;
            gload_lds16(ksrc, buf + (p * 256 + tid) * 16);
            const __bf16* vsrc = VT + ((size_t)((b * 8 + h) * 64 + r)) * Skv
                                    + kc * 64 + sgo;
            gload_lds16(vsrc, buf + 8192 + (p * 256 + tid) * 16);
        }
    };

    f32x4 acc[4] = {};
    float m_run = -1e30f, l_run = 0.f;

    const int nkc = CAUSAL ? (qc + 1) : (Skv >> 6);
    stageKV(smem, 0);
    int cur = 0;
    for (int kc = 0; kc < nkc; ++kc) {
        __syncthreads();
        if (kc + 1 < nkc) stageKV(smem + (cur ^ 1) * 16384, kc + 1);
        const char* Ksm = smem + cur * 16384;
        const char* Vsm = Ksm + 8192;

        f32x4 st[4];
#pragma unroll
        for (int f = 0; f < 4; ++f) {
            const char* kr = Ksm + (f * 16 + l15) * 128;
            bf16x8 ka0 = *(const bf16x8*)(kr + ((g ^ sw) * 16));
            bf16x8 ka1 = *(const bf16x8*)(kr + (((4 + g) ^ sw) * 16));
            f32x4 z = {};
            z = __builtin_amdgcn_mfma_f32_16x16x32_bf16(ka0, qf0, z, 0, 0, 0);
            st[f] = __builtin_amdgcn_mfma_f32_16x16x32_bf16(ka1, qf1, z, 0, 0, 0);
        }

        float rmax = -1e30f;
#pragma unroll
        for (int f = 0; f < 4; ++f)
#pragma unroll
            for (int j = 0; j < 4; ++j) {
                float v = st[f][j] * scale;
                if (CAUSAL) {
                    if (kc * 64 + f * 16 + g * 4 + j > sq) v = -1e30f;
                }
                st[f][j] = v;
                rmax = fmaxf(rmax, v);
            }
        rmax = fmaxf(rmax, __shfl_xor(rmax, 16, 64));
        rmax = fmaxf(rmax, __shfl_xor(rmax, 32, 64));
        const float mn = fmaxf(m_run, rmax);
        const float corr = __expf(m_run - mn);
        m_run = mn;
        float rsum = 0.f;
#pragma unroll
        for (int f = 0; f < 4; ++f)
#pragma unroll
            for (int j = 0; j < 4; ++j) {
                float p = __expf(st[f][j] - mn);
                st[f][j] = p;
                rsum += p;
            }
        rsum += __shfl_xor(rsum, 16, 64);
        rsum += __shfl_xor(rsum, 32, 64);
        l_run = l_run * corr + rsum;

#pragma unroll
        for (int j = 0; j < 4; ++j) {
            const float cj = __shfl(corr, g * 20 + j, 64);
            acc[0][j] *= cj; acc[1][j] *= cj; acc[2][j] *= cj; acc[3][j] *= cj;
        }

#pragma unroll
        for (int f = 0; f < 4; ++f)
#pragma unroll
            for (int j2 = 0; j2 < 2; ++j2) {
                union { __bf16 h2[2]; unsigned u; } cv;
                cv.h2[0] = (__bf16)st[f][2 * j2];
                cv.h2[1] = (__bf16)st[f][2 * j2 + 1];
                const int key0 = 16 * f + 4 * g + 2 * j2;
                const int byte = l15 * 128 + (((key0 >> 3) ^ sw) * 16) + (key0 & 7) * 2;
                *(unsigned*)(Psm + byte) = cv.u;
            }

#pragma unroll
        for (int ks = 0; ks < 2; ++ks) {
            const int so = ((4 * ks + g) ^ sw) * 16;
            bf16x8 pa = *(const bf16x8*)(Psm + l15 * 128 + so);
#pragma unroll
            for (int n = 0; n < 4; ++n) {
                bf16x8 vb = *(const bf16x8*)(Vsm + (n * 16 + l15) * 128 + so);
                acc[n] = __builtin_amdgcn_mfma_f32_16x16x32_bf16(pa, vb, acc[n], 0, 0, 0);
            }
        }
        cur ^= 1;
    }

    const float inv = 1.f / l_run;
#pragma unroll
    for (int j = 0; j < 4; ++j) {
        const float ij = __shfl(inv, g * 20 + j, 64);
        const int s = qc * 64 + w * 16 + g * 4 + j;
        __bf16* orow = Op + ((size_t)(b * Sq + s)) * D_MODEL + h * 64 + l15;
#pragma unroll
        for (int n = 0; n < 4; ++n)
            orow[n * 16] = (__bf16)(acc[n][j] * ij);
    }
}

// ---------------------------------------------------------------------------
// Residual add + LayerNorm: X fp32 + Y bf16 -> fp32 + bf16. One block/row.
// ---------------------------------------------------------------------------
__global__ __launch_bounds__(256) void add_ln(
    const float* __restrict__ X, const __bf16* __restrict__ Y,
    const float* __restrict__ w, const float* __restrict__ bias,
    float* __restrict__ Of, __bf16* __restrict__ Oh)
{
    const int t   = blockIdx.x;
    const int tid = threadIdx.x;
    const float2 x2 = *(const float2*)(X + (size_t)t * D_MODEL + tid * 2);
    const u16x2 yv = *(const u16x2*)(Y + (size_t)t * D_MODEL + tid * 2);
    union { u16x2 u; __bf16 h2[2]; } yc; yc.u = yv;
    float v0 = x2.x + (float)yc.h2[0], v1 = x2.y + (float)yc.h2[1];
    float sum = v0 + v1;
    float sq  = v0 * v0 + v1 * v1;
#pragma unroll
    for (int off = 32; off; off >>= 1) {
        sum += __shfl_xor(sum, off);
        sq  += __shfl_xor(sq, off);
    }
    __shared__ float ssum[4], ssq[4];
    const int wid = tid >> 6;
    if ((tid & 63) == 0) { ssum[wid] = sum; ssq[wid] = sq; }
    __syncthreads();
    sum = ssum[0] + ssum[1] + ssum[2] + ssum[3];
    sq  = ssq[0] + ssq[1] + ssq[2] + ssq[3];

    const float mu  = sum * (1.f / D_MODEL);
    const float var = sq * (1.f / D_MODEL) - mu * mu;
    const float rs  = rsqrtf(var + EPS_LN);
    const float2 w2 = *(const float2*)(w + tid * 2);
    const float2 b2 = *(const float2*)(bias + tid * 2);
    float o0 = (v0 - mu) * rs * w2.x + b2.x;
    float o1 = (v1 - mu) * rs * w2.y + b2.y;
    *(float2*)(Of + (size_t)t * D_MODEL + tid * 2) = make_float2(o0, o1);
    union { __bf16 h2[2]; u16x2 u; } cv;
    cv.h2[0] = (__bf16)o0; cv.h2[1] = (__bf16)o1;
    *(u16x2*)(Oh + (size_t)t * D_MODEL + tid * 2) = cv.u;
}

// ---------------------------------------------------------------------------
// src [s][b][512] -> permuted [b][s][512], fp32 + bf16.  grid = 8192.
// ---------------------------------------------------------------------------
__global__ __launch_bounds__(256) void permute_src(
    const float* __restrict__ src, float* __restrict__ Of, __bf16* __restrict__ Oh)
{
    const int t = blockIdx.x;            // b*512 + s
    const int b = t >> 9, s = t & 511;
    const int tid = threadIdx.x;
    const float2 v = *(const float2*)(src + ((size_t)(s * BATCH + b)) * D_MODEL + tid * 2);
    *(float2*)(Of + (size_t)t * D_MODEL + tid * 2) = v;
    union { __bf16 h2[2]; u16x2 u; } cv;
    cv.h2[0] = (__bf16)v.x; cv.h2[1] = (__bf16)v.y;
    *(u16x2*)(Oh + (size_t)t * D_MODEL + tid * 2) = cv.u;
}

// ---------------------------------------------------------------------------
// Token embedding + posenc -> [b][s][512], fp32 + bf16. One block per row.
// ---------------------------------------------------------------------------
__global__ __launch_bounds__(256) void embed_pos(
    const int* __restrict__ tokens, const float* __restrict__ emb,
    float* __restrict__ Of, __bf16* __restrict__ Oh)
{
    const int t   = blockIdx.x;          // b*128 + s
    const int b   = t >> 7, s = t & 127;
    const int tid = threadIdx.x;
    const int tok = tokens[s * BATCH + b];
    const float C = 9.210340371976184f / 256.f;
    const int d = tid * 2;
    const int j = (d < 256) ? d : (d - 256);
    float a0 = (float)s * expf(-(float)j * C);
    float a1 = (float)s * expf(-(float)(j + 1) * C);
    float pe0 = (d < 256) ? sinf(a0) : cosf(a0);
    float pe1 = (d < 256) ? sinf(a1) : cosf(a1);
    const float2 e2 = *(const float2*)(emb + (size_t)tok * D_MODEL + d);
    float o0 = e2.x + pe0, o1 = e2.y + pe1;
    *(float2*)(Of + (size_t)t * D_MODEL + d) = make_float2(o0, o1);
    union { __bf16 h2[2]; u16x2 u; } cv;
    cv.h2[0] = (__bf16)o0; cv.h2[1] = (__bf16)o1;
    *(u16x2*)(Oh + (size_t)t * D_MODEL + d) = cv.u;
}

// ---------------------------------------------------------------------------
// Multi-segment fp32 -> bf16 conversion (up to 12 segments, n%8==0 each).
// ---------------------------------------------------------------------------
struct CvtSeg { const float* s; __bf16* d; int n8; };
struct CvtArgs { CvtSeg seg[12]; int tot8; };

__global__ __launch_bounds__(256) void cvt_multi(CvtArgs a)
{
    const int stride = gridDim.x * 256;
    for (int u = blockIdx.x * 256 + threadIdx.x; u < a.tot8; u += stride) {
        int v = u;
        for (int sgi = 0; sgi < 12; ++sgi) {
            const int n8 = a.seg[sgi].n8;
            if (v < n8) {
                const float4 f0 = ((const float4*)a.seg[sgi].s)[v * 2];
                const float4 f1 = ((const float4*)a.seg[sgi].s)[v * 2 + 1];
                union { __bf16 h[8]; u16x8 u; } c;
                c.h[0] = (__bf16)f0.x; c.h[1] = (__bf16)f0.y;
                c.h[2] = (__bf16)f0.z; c.h[3] = (__bf16)f0.w;
                c.h[4] = (__bf16)f1.x; c.h[5] = (__bf16)f1.y;
                c.h[6] = (__bf16)f1.z; c.h[7] = (__bf16)f1.w;
                ((u16x8*)a.seg[sgi].d)[v] = c.u;
                break;
            }
            v -= n8;
        }
    }
}

__global__ __launch_bounds__(256) void pad_outw(
    const float* __restrict__ w, __bf16* __restrict__ o)
{
    const int idx = blockIdx.x * 256 + threadIdx.x;
    const int r = idx >> 9;
    const int c = idx & 511;
    o[idx] = (__bf16)(r < 97 ? w[r * 512 + c] : 0.f);
}

// ---------------------------------------------------------------------------
// Host orchestration
// ---------------------------------------------------------------------------
extern "C" void kernel_launch(void* const* d_in, const int* in_sizes, int n_in,
                              void* d_out, int out_size, void* d_ws, size_t ws_size,
                              hipStream_t stream)
{
    const float* src     = (const float*)d_in[0];
    const int*   tokens  = (const int*)d_in[1];
    const float* tok_emb = (const float*)d_in[2];
    const float* enc_qkv_w = (const float*)d_in[3];
    const float* enc_qkv_b = (const float*)d_in[4];
    const float* enc_out_w = (const float*)d_in[5];
    const float* enc_out_b = (const float*)d_in[6];
    const float* enc_l1_w  = (const float*)d_in[7];
    const float* enc_l1_b  = (const float*)d_in[8];
    const float* enc_l2_w  = (const float*)d_in[9];
    const float* enc_l2_b  = (const float*)d_in[10];
    const float* enc_n1_w  = (const float*)d_in[11];
    const float* enc_n1_b  = (const float*)d_in[12];
    const float* enc_n2_w  = (const float*)d_in[13];
    const float* enc_n2_b  = (const float*)d_in[14];
    const float* dec_qkv_w = (const float*)d_in[15];
    const float* dec_qkv_b = (const float*)d_in[16];
    const float* dec_sout_w = (const float*)d_in[17];
    const float* dec_sout_b = (const float*)d_in[18];
    const float* dec_q_w   = (const float*)d_in[19];
    const float* dec_q_b   = (const float*)d_in[20];
    const float* dec_k_w   = (const float*)d_in[21];
    const float* dec_k_b   = (const float*)d_in[22];
    const float* dec_v_w   = (const float*)d_in[23];
    const float* dec_v_b   = (const float*)d_in[24];
    const float* dec_cout_w = (const float*)d_in[25];
    const float* dec_cout_b = (const float*)d_in[26];
    const float* dec_l1_w  = (const float*)d_in[27];
    const float* dec_l1_b  = (const float*)d_in[28];
    const float* dec_l2_w  = (const float*)d_in[29];
    const float* dec_l2_b  = (const float*)d_in[30];
    const float* dec_n1_w  = (const float*)d_in[31];
    const float* dec_n1_b  = (const float*)d_in[32];
    const float* dec_n2_w  = (const float*)d_in[33];
    const float* dec_n2_b  = (const float*)d_in[34];
    const float* dec_n3_w  = (const float*)d_in[35];
    const float* dec_n3_b  = (const float*)d_in[36];
    const float* out_w     = (const float*)d_in[37];
    const float* out_b     = (const float*)d_in[38];

    const int NE = 512 * BATCH;   // 8192 rows, [b][s]
    const int ND = 128 * BATCH;   // 2048 rows, [b][s]
    const float scale = 0.125f;
    const int BIG = 1 << 30;

    // -------- workspace layout (bytes) --------
    char* w8 = (char*)d_ws;
    float*  Ax_f = (float*) (w8 + 0);          // 16 MB enc residual fp32
    float*  T_f  = (float*) (w8 + 16777216);   //  4 MB dec residual fp32
    __bf16* Ax_h = (__bf16*)(w8 + 20971520);   //  8 MB enc bf16
    __bf16* T_h  = (__bf16*)(w8 + 29360128);   //  2 MB dec bf16
    __bf16* AO_h = (__bf16*)(w8 + 31457280);   //  8 MB attn out bf16
    __bf16* Y_h  = (__bf16*)(w8 + 39845888);   //  8 MB residual-Y bf16
    __bf16* VT   = (__bf16*)(w8 + 48234496);   //  8 MB V-transpose
    __bf16* OWp  = (__bf16*)(w8 + 56623104);   //  0.13 MB padded out_w
    char*   Gb   = w8 + 56754176;              // 33.5 MB union
    __bf16* Gqk  = (__bf16*)Gb;                // qk bf16 [N][1024]
    __bf16* Gh   = (__bf16*)Gb;                // ffn hidden bf16 [N][2048]
    __bf16* Gq   = (__bf16*)Gb;                // cross q bf16 [2048][512]
    __bf16* Gk   = (__bf16*)(Gb + 2097152);    // cross k bf16 [8192][512]
    __bf16* WB   = (__bf16*)(w8 + 90308608);   // weights: 88 MB (upfront) or 9.4 MB

    const bool upfront = ws_size >= (size_t)178388992;

    auto gemmS = [&](const __bf16* Am, const __bf16* Wm, const float* bv,
                     void* C, int N, int M, int K, int relu) {
        // swapped epilogue, bf16 out, full tiles, MS = M
        const int nb128 = (M / 128) * (N / 128);
        if (nb128 >= 256) {
            dim3 grid(M / 128, N / 128);
            gemm_mfma<128, 1, 1><<<grid, 256, 0, stream>>>(
                Am, Wm, nullptr, BIG, bv, nullptr, 0, C, nullptr, BIG, 0,
                N, M, M, K, relu, 0);
        } else {
            dim3 grid(M / 128, N / 64);
            gemm_mfma<64, 1, 1><<<grid, 256, 0, stream>>>(
                Am, Wm, nullptr, BIG, bv, nullptr, 0, C, nullptr, BIG, 0,
                N, M, M, K, relu, 0);
        }
    };
    auto gemmN = [&](const __bf16* Am, const __bf16* Wm, const __bf16* W2m, int wsplit,
                     const float* bv, const float* bv2, int bsplit,
                     void* C, __bf16* VTp, int m_vt0, int log2S,
                     int N, int M, int MS, int K, bool outbf, int permrow) {
        const int nb128 = ((M + 127) / 128) * (N / 128);
        if (nb128 >= 256) {
            dim3 grid((M + 127) / 128, N / 128);
            if (outbf) gemm_mfma<128, 1, 0><<<grid, 256, 0, stream>>>(
                Am, Wm, W2m, wsplit, bv, bv2, bsplit, C, VTp, m_vt0, log2S,
                N, M, MS, K, 0, permrow);
            else       gemm_mfma<128, 0, 0><<<grid, 256, 0, stream>>>(
                Am, Wm, W2m, wsplit, bv, bv2, bsplit, C, VTp, m_vt0, log2S,
                N, M, MS, K, 0, permrow);
        } else {
            dim3 grid((M + 127) / 128, N / 64);
            if (outbf) gemm_mfma<64, 1, 0><<<grid, 256, 0, stream>>>(
                Am, Wm, W2m, wsplit, bv, bv2, bsplit, C, VTp, m_vt0, log2S,
                N, M, MS, K, 0, permrow);
            else       gemm_mfma<64, 0, 0><<<grid, 256, 0, stream>>>(
                Am, Wm, W2m, wsplit, bv, bv2, bsplit, C, VTp, m_vt0, log2S,
                N, M, MS, K, 0, permrow);
        }
    };
    auto cvt = [&](CvtArgs& a, int blocks) {
        int tot = 0;
        for (int i = 0; i < 12; ++i) tot += a.seg[i].n8;
        a.tot8 = tot;
        cvt_multi<<<blocks, 256, 0, stream>>>(a);
    };

    // ---- upfront: permute src, pad out_w, (mega-)convert weights ----
    permute_src<<<NE, 256, 0, stream>>>(src, Ax_f, Ax_h);
    pad_outw<<<256, 256, 0, stream>>>(out_w, OWp);

    // upfront weight block offsets (elements)
    __bf16* WencQKV = WB;
    __bf16* WencOUT = WencQKV + 4718592;
    __bf16* WencL1  = WencOUT + 1572864;
    __bf16* WencL2  = WencL1 + 6291456;
    __bf16* WdecQKV = WencL2 + 6291456;
    __bf16* WdecSOUT = WdecQKV + 4718592;
    __bf16* WdecQ   = WdecSOUT + 1572864;
    __bf16* WdecK   = WdecQ + 1572864;
    __bf16* WdecV   = WdecK + 1572864;
    __bf16* WdecCOUT = WdecV + 1572864;
    __bf16* WdecL1  = WdecCOUT + 1572864;
    __bf16* WdecL2  = WdecL1 + 6291456;

    if (upfront) {
        CvtArgs a = {};
        a.seg[0]  = { enc_qkv_w,  WencQKV,  4718592 / 8 };
        a.seg[1]  = { enc_out_w,  WencOUT,  1572864 / 8 };
        a.seg[2]  = { enc_l1_w,   WencL1,   6291456 / 8 };
        a.seg[3]  = { enc_l2_w,   WencL2,   6291456 / 8 };
        a.seg[4]  = { dec_qkv_w,  WdecQKV,  4718592 / 8 };
        a.seg[5]  = { dec_sout_w, WdecSOUT, 1572864 / 8 };
        a.seg[6]  = { dec_q_w,    WdecQ,    1572864 / 8 };
        a.seg[7]  = { dec_k_w,    WdecK,    1572864 / 8 };
        a.seg[8]  = { dec_v_w,    WdecV,    1572864 / 8 };
        a.seg[9]  = { dec_cout_w, WdecCOUT, 1572864 / 8 };
        a.seg[10] = { dec_l1_w,   WdecL1,   6291456 / 8 };
        a.seg[11] = { dec_l2_w,   WdecL2,   6291456 / 8 };
        cvt(a, 2048);
    }

    // ---------------- Encoder ----------------
    for (int i = 0; i < 6; ++i) {
        __bf16 *wqkv, *wout, *wl1, *wl2;
        if (upfront) {
            wqkv = WencQKV + (size_t)i * 786432;
            wout = WencOUT + (size_t)i * 262144;
            wl1  = WencL1 + (size_t)i * 1048576;
            wl2  = WencL2 + (size_t)i * 1048576;
        } else {
            wqkv = WB; wout = WB + 786432; wl1 = WB + 1048576; wl2 = WB + 2097152;
            CvtArgs a = {};
            a.seg[0] = { enc_qkv_w + (size_t)i * 786432,  wqkv, 786432 / 8 };
            a.seg[1] = { enc_out_w + (size_t)i * 262144,  wout, 262144 / 8 };
            a.seg[2] = { enc_l1_w  + (size_t)i * 1048576, wl1, 1048576 / 8 };
            a.seg[3] = { enc_l2_w  + (size_t)i * 1048576, wl2, 1048576 / 8 };
            cvt(a, 1024);
        }

        // QKV: Q,K -> Gqk (stride 1024), V -> VT directly
        gemmN(Ax_h, wqkv, nullptr, BIG, enc_qkv_b + (size_t)i * 1536, nullptr, 0,
              Gqk, VT, 1024, 9, NE, 1536, 1024, 512, true, 0);
        attn_mfma<0><<<dim3(8, 8, BATCH), 256, 0, stream>>>(
            Gqk, Gqk, VT, AO_h, 512, 512, 1024, 1024, 512, scale);
        gemmS(AO_h, wout, enc_out_b + (size_t)i * 512, Y_h, NE, 512, 512, 0);
        add_ln<<<NE, 256, 0, stream>>>(Ax_f, Y_h,
                                       enc_n1_w + (size_t)i * 512, enc_n1_b + (size_t)i * 512,
                                       Ax_f, Ax_h);
        gemmS(Ax_h, wl1, enc_l1_b + (size_t)i * 2048, Gh, NE, 2048, 512, 1);
        gemmS(Gh, wl2, enc_l2_b + (size_t)i * 512, Y_h, NE, 512, 2048, 0);
        add_ln<<<NE, 256, 0, stream>>>(Ax_f, Y_h,
                                       enc_n2_w + (size_t)i * 512, enc_n2_b + (size_t)i * 512,
                                       Ax_f, Ax_h);
    }

    // ---------------- Decoder ----------------
    embed_pos<<<ND, 256, 0, stream>>>(tokens, tok_emb, T_f, T_h);
    for (int i = 0; i < 6; ++i) {
        __bf16 *dqkv, *dsout, *dq, *dk, *dv, *dcout, *dl1, *dl2;
        if (upfront) {
            dqkv  = WdecQKV + (size_t)i * 786432;
            dsout = WdecSOUT + (size_t)i * 262144;
            dq    = WdecQ + (size_t)i * 262144;
            dk    = WdecK + (size_t)i * 262144;
            dv    = WdecV + (size_t)i * 262144;
            dcout = WdecCOUT + (size_t)i * 262144;
            dl1   = WdecL1 + (size_t)i * 1048576;
            dl2   = WdecL2 + (size_t)i * 1048576;
        } else {
            dqkv = WB; dsout = WB + 786432; dq = WB + 1048576; dk = WB + 1310720;
            dv = WB + 1572864; dcout = WB + 1835008; dl1 = WB + 2097152; dl2 = WB + 3145728;
            CvtArgs a = {};
            a.seg[0] = { dec_qkv_w  + (size_t)i * 786432,  dqkv,  786432 / 8 };
            a.seg[1] = { dec_sout_w + (size_t)i * 262144,  dsout, 262144 / 8 };
            a.seg[2] = { dec_q_w    + (size_t)i * 262144,  dq,    262144 / 8 };
            a.seg[3] = { dec_k_w    + (size_t)i * 262144,  dk,    262144 / 8 };
            a.seg[4] = { dec_v_w    + (size_t)i * 262144,  dv,    262144 / 8 };
            a.seg[5] = { dec_cout_w + (size_t)i * 262144,  dcout, 262144 / 8 };
            a.seg[6] = { dec_l1_w   + (size_t)i * 1048576, dl1,  1048576 / 8 };
            a.seg[7] = { dec_l2_w   + (size_t)i * 1048576, dl2,  1048576 / 8 };
            cvt(a, 1024);
        }

        // causal self-attn: Q,K -> Gqk, V -> VT (S=128)
        gemmN(T_h, dqkv, nullptr, BIG, dec_qkv_b + (size_t)i * 1536, nullptr, 0,
              Gqk, VT, 1024, 7, ND, 1536, 1024, 512, true, 0);
        attn_mfma<1><<<dim3(2, 8, BATCH), 256, 0, stream>>>(
            Gqk, Gqk, VT, AO_h, 128, 128, 1024, 1024, 512, scale);
        gemmS(AO_h, dsout, dec_sout_b + (size_t)i * 512, Y_h, ND, 512, 512, 0);
        add_ln<<<ND, 256, 0, stream>>>(T_f, Y_h,
                                       dec_n1_w + (size_t)i * 512, dec_n1_b + (size_t)i * 512,
                                       T_f, T_h);
        // cross-attn: q -> Gq; merged K|V: K -> Gk, V -> VT (S=512)
        gemmS(T_h, dq, dec_q_b + (size_t)i * 512, Gq, ND, 512, 512, 0);
        gemmN(Ax_h, dk, dv, 512, dec_k_b + (size_t)i * 512, dec_v_b + (size_t)i * 512, 512,
              Gk, VT, 512, 9, NE, 1024, 512, 512, true, 0);
        attn_mfma<0><<<dim3(2, 8, BATCH), 256, 0, stream>>>(
            Gq, Gk, VT, AO_h, 128, 512, 512, 512, 0, scale);
        gemmS(AO_h, dcout, dec_cout_b + (size_t)i * 512, Y_h, ND, 512, 512, 0);
        add_ln<<<ND, 256, 0, stream>>>(T_f, Y_h,
                                       dec_n2_w + (size_t)i * 512, dec_n2_b + (size_t)i * 512,
                                       T_f, T_h);
        // FFN
        gemmS(T_h, dl1, dec_l1_b + (size_t)i * 2048, Gh, ND, 2048, 512, 1);
        gemmS(Gh, dl2, dec_l2_b + (size_t)i * 512, Y_h, ND, 512, 2048, 0);
        add_ln<<<ND, 256, 0, stream>>>(T_f, Y_h,
                                       dec_n3_w + (size_t)i * 512, dec_n3_b + (size_t)i * 512,
                                       T_f, T_h);
    }

    // ---------------- Output projection (rows permuted back to [s][b]) ----
    gemmN(T_h, OWp, nullptr, BIG, out_b, nullptr, 0,
          (float*)d_out, nullptr, BIG, 7, ND, 97, 97, 512, false, 1);
}

// Round 6
// 1533.745 us; speedup vs baseline: 6.4851x; 1.0768x over previous
//
#include <hip/hip_runtime.h>
#include <hip/hip_bf16.h>
#include <cstddef>
#include <cstdint>

#define D_MODEL 512
#define BATCH 16
#define EPS_LN 1e-5f

typedef __bf16 bf16x8 __attribute__((ext_vector_type(8)));
typedef float f32x4 __attribute__((ext_vector_type(4)));
typedef unsigned short u16x8 __attribute__((ext_vector_type(8)));
typedef unsigned short u16x4 __attribute__((ext_vector_type(4)));
typedef unsigned short u16x2 __attribute__((ext_vector_type(2)));

__device__ __forceinline__ void gload_lds16(const void* g, void* l) {
    __builtin_amdgcn_global_load_lds(
        (const __attribute__((address_space(1))) void*)g,
        (__attribute__((address_space(3))) void*)l,
        16, 0, 0);
}

// ---------------------------------------------------------------------------
// MFMA bf16 NT GEMM, activations [b][s][*] (row r = b*S + s).
//   C[r, c] = act(A[r,:] . Wrow[c,:] + bias[c])
// Tile BM x 128, BK=64, 512 threads (8 waves, 2x4), double-buffered 2-phase.
// BM=128: 2 blk/CU (64KB LDS), wave tile 64x32 (4x2 frags).
// BM=64:  3 blk/CU (48KB LDS), wave tile 32x32 (2x2 frags) - skinny GEMMs.
// SWAP=1: swapped-operand epilogue -> vector stores, bf16, full tiles.
// SWAP=0: classic; col guard (c<Mlim), VT side-output (c>=m_vt0), dual bias
//         (c>=bsplit->bias2), W split (c>=wsplit->W2), permrow on store.
// ---------------------------------------------------------------------------
template <int BM, int OUTBF16, int SWAP>
__global__ __launch_bounds__(512) void gemm_mfma(
    const __bf16* __restrict__ A, const __bf16* __restrict__ W,
    const __bf16* __restrict__ W2, int wsplit,
    const float* __restrict__ bias, const float* __restrict__ bias2, int bsplit,
    void* __restrict__ Cout, __bf16* __restrict__ VTout, int m_vt0, int log2S,
    int N, int Mlim, int MS, int K, int relu, int permrow)
{
    constexpr int MR     = BM / 32;        // 4 or 2 row frags per wave
    constexpr int WRSPAN = BM / 2;         // rows per wave-row
    constexpr int ABYTES = BM * 128;
    constexpr int PA     = ABYTES / 8192;  // A staging passes (2 or 1)
    constexpr int BUFB   = ABYTES + 16384;

    __shared__ __align__(16) char smem[2 * BUFB];

    const int tid  = threadIdx.x;
    const int lane = tid & 63;
    const int wid  = tid >> 6;        // 0..7
    const int wrow = wid >> 2;        // 0..1
    const int wcol = wid & 3;         // 0..3
    const int row0 = blockIdx.y * BM;
    const int col0 = blockIdx.x * 128;

    const int lrow  = lane & 15;
    const int lhalf = lane >> 4;
    const int koff0 = ((lhalf) ^ (lrow & 7)) * 16;
    const int koff1 = ((4 + lhalf) ^ (lrow & 7)) * 16;

    const int srow = tid >> 3;        // 0..63
    const int slot = tid & 7;
    const int sg   = slot ^ (srow & 7);

    f32x4 acc[MR][2] = {};

    const __bf16* Wsel = W;
    int wc0 = col0;
    if (col0 >= wsplit) { Wsel = W2; wc0 = col0 - wsplit; }

    const __bf16* Abase = A + (size_t)(row0 + srow) * K + sg * 8;
    const __bf16* Wbase = Wsel + (size_t)(wc0 + srow) * K + sg * 8;

    auto stage = [&](char* buf, int kt) {
#pragma unroll
        for (int p = 0; p < PA; ++p)
            gload_lds16(Abase + (size_t)p * 64 * K + kt, buf + p * 8192 + tid * 16);
#pragma unroll
        for (int p = 0; p < 2; ++p)
            gload_lds16(Wbase + (size_t)p * 64 * K + kt,
                        buf + ABYTES + p * 8192 + tid * 16);
    };

    stage(smem, 0);
    const int nkt = K >> 6;
    int cur = 0;
    for (int kt = 0; kt < nkt; ++kt) {
        __syncthreads();
        if (kt + 1 < nkt) stage(smem + (cur ^ 1) * BUFB, (kt + 1) * 64);
        const char* aB = smem + cur * BUFB + (wrow * WRSPAN + lrow) * 128;
        const char* wB = smem + cur * BUFB + ABYTES + (wcol * 32 + lrow) * 128;
#pragma unroll
        for (int ks = 0; ks < 2; ++ks) {
            const int ko = ks ? koff1 : koff0;
            bf16x8 af[MR], bfr[2];
#pragma unroll
            for (int m = 0; m < MR; ++m) af[m]  = *(const bf16x8*)(aB + m * 2048 + ko);
#pragma unroll
            for (int n = 0; n < 2; ++n)  bfr[n] = *(const bf16x8*)(wB + n * 2048 + ko);
            if (SWAP) {
#pragma unroll
                for (int m = 0; m < MR; ++m)
#pragma unroll
                    for (int n = 0; n < 2; ++n)
                        acc[m][n] = __builtin_amdgcn_mfma_f32_16x16x32_bf16(
                            bfr[n], af[m], acc[m][n], 0, 0, 0);
            } else {
#pragma unroll
                for (int m = 0; m < MR; ++m)
#pragma unroll
                    for (int n = 0; n < 2; ++n)
                        acc[m][n] = __builtin_amdgcn_mfma_f32_16x16x32_bf16(
                            af[m], bfr[n], acc[m][n], 0, 0, 0);
            }
        }
        cur ^= 1;
    }

    if (SWAP) {
        // D^T: lane owns row r; 4 consecutive cols per acc reg
#pragma unroll
        for (int m = 0; m < MR; ++m) {
            const int r = row0 + wrow * WRSPAN + m * 16 + lrow;
#pragma unroll
            for (int n = 0; n < 2; ++n) {
                const int c0 = col0 + wcol * 32 + n * 16 + lhalf * 4;
                const float4 bv = *(const float4*)(bias + c0);
                float o0 = acc[m][n][0] + bv.x, o1 = acc[m][n][1] + bv.y;
                float o2 = acc[m][n][2] + bv.z, o3 = acc[m][n][3] + bv.w;
                if (relu) {
                    o0 = fmaxf(o0, 0.f); o1 = fmaxf(o1, 0.f);
                    o2 = fmaxf(o2, 0.f); o3 = fmaxf(o3, 0.f);
                }
                if (OUTBF16) {
                    union { __bf16 h4[4]; u16x4 u; } pk;
                    pk.h4[0] = (__bf16)o0; pk.h4[1] = (__bf16)o1;
                    pk.h4[2] = (__bf16)o2; pk.h4[3] = (__bf16)o3;
                    *(u16x4*)((__bf16*)Cout + (size_t)r * MS + c0) = pk.u;
                } else {
                    *(float4*)((float*)Cout + (size_t)r * MS + c0) =
                        make_float4(o0, o1, o2, o3);
                }
            }
        }
    } else {
        const int orow = row0 + wrow * WRSPAN + lhalf * 4;
        const int ocol = col0 + wcol * 32 + lrow;
        const int smask = (1 << log2S) - 1;
#pragma unroll
        for (int n = 0; n < 2; ++n) {
            const int c = ocol + n * 16;
            if (c >= m_vt0) {
                const int cv = c - m_vt0;
                const int hh = cv >> 6, dd = cv & 63;
                const float bv = (bias2 && c >= bsplit) ? bias2[c - bsplit] : bias[c];
#pragma unroll
                for (int m = 0; m < MR; ++m) {
                    const int rr = orow + m * 16;
                    const int bb = rr >> log2S, ss = rr & smask;
                    union { __bf16 h4[4]; u16x4 u; } pk;
#pragma unroll
                    for (int j = 0; j < 4; ++j)
                        pk.h4[j] = (__bf16)(acc[m][n][j] + bv);
                    *(u16x4*)(VTout + (((size_t)((bb * 8 + hh) * 64 + dd)) << log2S) + ss) = pk.u;
                }
            } else if (c < Mlim) {
                const float bv = (bias2 && c >= bsplit) ? bias2[c - bsplit] : bias[c];
#pragma unroll
                for (int m = 0; m < MR; ++m) {
#pragma unroll
                    for (int j = 0; j < 4; ++j) {
                        int rr = orow + m * 16 + j;
                        if (permrow) rr = ((rr & smask) * BATCH) + (rr >> log2S);
                        float v = acc[m][n][j] + bv;
                        if (relu) v = fmaxf(v, 0.f);
                        if (OUTBF16) ((__bf16*)Cout)[(size_t)rr * MS + c] = (__bf16)v;
                        else         ((float*)Cout)[(size_t)rr * MS + c] = v;
                    }
                }
            }
        }
    }
}

// ---------------------------------------------------------------------------
// MFMA flash attention, [b][s][*] layout, double-buffered K/V staging.
// Block = 64 q-rows (4 waves x 16), 64-key chunks. grid (Sq/64, 8, 16).
// VT: [((b*8+h)*64+d)][Skv].
// ---------------------------------------------------------------------------
template <int CAUSAL>
__global__ __launch_bounds__(256) void attn_mfma(
    const __bf16* __restrict__ Qb, const __bf16* __restrict__ Kb,
    const __bf16* __restrict__ VT, __bf16* __restrict__ Op,
    int Sq, int Skv, int qstride, int kstride, int koff, float scale)
{
    __shared__ __align__(16) char smem[40960];
    const int tid = threadIdx.x;
    const int l   = tid & 63;
    const int w   = tid >> 6;
    char* Psm = smem + 32768 + w * 2048;

    const int qc = blockIdx.x;
    const int h  = blockIdx.y;
    const int b  = blockIdx.z;
    const int l15 = l & 15;
    const int g   = l >> 4;
    const int sw  = l15 & 7;

    const int sq = qc * 64 + w * 16 + l15;
    const __bf16* qrow = Qb + ((size_t)(b * Sq + sq)) * qstride + h * 64 + g * 8;
    const bf16x8 qf0 = *(const bf16x8*)(qrow);
    const bf16x8 qf1 = *(const bf16x8*)(qrow + 32);

    const int srow = tid >> 3;
    const int slot = tid & 7;

    auto stageKV = [&](char* buf, int kc) {
#pragma unroll
        for (int p = 0; p < 2; ++p) {
            const int r   = p * 32 + srow;
            const int sgo = (slot ^ (r & 7)) * 8;
            const __bf16* ksrc = Kb + ((size_t)(b * Skv + kc * 64 + r)) * kstride
                                    + koff + h * 64 + sgo;
            gload_lds16(ksrc, buf + (p * 256 + tid) * 16);
            const __bf16* vsrc = VT + ((size_t)((b * 8 + h) * 64 + r)) * Skv
                                    + kc * 64 + sgo;
            gload_lds16(vsrc, buf + 8192 + (p * 256 + tid) * 16);
        }
    };

    f32x4 acc[4] = {};
    float m_run = -1e30f, l_run = 0.f;

    const int nkc = CAUSAL ? (qc + 1) : (Skv >> 6);
    stageKV(smem, 0);
    int cur = 0;
    for (int kc = 0; kc < nkc; ++kc) {
        __syncthreads();
        if (kc + 1 < nkc) stageKV(smem + (cur ^ 1) * 16384, kc + 1);
        const char* Ksm = smem + cur * 16384;
        const char* Vsm = Ksm + 8192;

        f32x4 st[4];
#pragma unroll
        for (int f = 0; f < 4; ++f) {
            const char* kr = Ksm + (f * 16 + l15) * 128;
            bf16x8 ka0 = *(const bf16x8*)(kr + ((g ^ sw) * 16));
            bf16x8 ka1 = *(const bf16x8*)(kr + (((4 + g) ^ sw) * 16));
            f32x4 z = {};
            z = __builtin_amdgcn_mfma_f32_16x16x32_bf16(ka0, qf0, z, 0, 0, 0);
            st[f] = __builtin_amdgcn_mfma_f32_16x16x32_bf16(ka1, qf1, z, 0, 0, 0);
        }

        float rmax = -1e30f;
#pragma unroll
        for (int f = 0; f < 4; ++f)
#pragma unroll
            for (int j = 0; j < 4; ++j) {
                float v = st[f][j] * scale;
                if (CAUSAL) {
                    if (kc * 64 + f * 16 + g * 4 + j > sq) v = -1e30f;
                }
                st[f][j] = v;
                rmax = fmaxf(rmax, v);
            }
        rmax = fmaxf(rmax, __shfl_xor(rmax, 16, 64));
        rmax = fmaxf(rmax, __shfl_xor(rmax, 32, 64));
        const float mn = fmaxf(m_run, rmax);
        const float corr = __expf(m_run - mn);
        m_run = mn;
        float rsum = 0.f;
#pragma unroll
        for (int f = 0; f < 4; ++f)
#pragma unroll
            for (int j = 0; j < 4; ++j) {
                float p = __expf(st[f][j] - mn);
                st[f][j] = p;
                rsum += p;
            }
        rsum += __shfl_xor(rsum, 16, 64);
        rsum += __shfl_xor(rsum, 32, 64);
        l_run = l_run * corr + rsum;

#pragma unroll
        for (int j = 0; j < 4; ++j) {
            const float cj = __shfl(corr, g * 20 + j, 64);
            acc[0][j] *= cj; acc[1][j] *= cj; acc[2][j] *= cj; acc[3][j] *= cj;
        }

#pragma unroll
        for (int f = 0; f < 4; ++f)
#pragma unroll
            for (int j2 = 0; j2 < 2; ++j2) {
                union { __bf16 h2[2]; unsigned u; } cv;
                cv.h2[0] = (__bf16)st[f][2 * j2];
                cv.h2[1] = (__bf16)st[f][2 * j2 + 1];
                const int key0 = 16 * f + 4 * g + 2 * j2;
                const int byte = l15 * 128 + (((key0 >> 3) ^ sw) * 16) + (key0 & 7) * 2;
                *(unsigned*)(Psm + byte) = cv.u;
            }

#pragma unroll
        for (int ks = 0; ks < 2; ++ks) {
            const int so = ((4 * ks + g) ^ sw) * 16;
            bf16x8 pa = *(const bf16x8*)(Psm + l15 * 128 + so);
#pragma unroll
            for (int n = 0; n < 4; ++n) {
                bf16x8 vb = *(const bf16x8*)(Vsm + (n * 16 + l15) * 128 + so);
                acc[n] = __builtin_amdgcn_mfma_f32_16x16x32_bf16(pa, vb, acc[n], 0, 0, 0);
            }
        }
        cur ^= 1;
    }

    const float inv = 1.f / l_run;
#pragma unroll
    for (int j = 0; j < 4; ++j) {
        const float ij = __shfl(inv, g * 20 + j, 64);
        const int s = qc * 64 + w * 16 + g * 4 + j;
        __bf16* orow = Op + ((size_t)(b * Sq + s)) * D_MODEL + h * 64 + l15;
#pragma unroll
        for (int n = 0; n < 4; ++n)
            orow[n * 16] = (__bf16)(acc[n][j] * ij);
    }
}

// ---------------------------------------------------------------------------
// Residual add + LayerNorm: X fp32 + Y bf16 -> fp32 + bf16. One block/row.
// ---------------------------------------------------------------------------
__global__ __launch_bounds__(256) void add_ln(
    const float* __restrict__ X, const __bf16* __restrict__ Y,
    const float* __restrict__ w, const float* __restrict__ bias,
    float* __restrict__ Of, __bf16* __restrict__ Oh)
{
    const int t   = blockIdx.x;
    const int tid = threadIdx.x;
    const float2 x2 = *(const float2*)(X + (size_t)t * D_MODEL + tid * 2);
    const u16x2 yv = *(const u16x2*)(Y + (size_t)t * D_MODEL + tid * 2);
    union { u16x2 u; __bf16 h2[2]; } yc; yc.u = yv;
    float v0 = x2.x + (float)yc.h2[0], v1 = x2.y + (float)yc.h2[1];
    float sum = v0 + v1;
    float sq  = v0 * v0 + v1 * v1;
#pragma unroll
    for (int off = 32; off; off >>= 1) {
        sum += __shfl_xor(sum, off);
        sq  += __shfl_xor(sq, off);
    }
    __shared__ float ssum[4], ssq[4];
    const int wid = tid >> 6;
    if ((tid & 63) == 0) { ssum[wid] = sum; ssq[wid] = sq; }
    __syncthreads();
    sum = ssum[0] + ssum[1] + ssum[2] + ssum[3];
    sq  = ssq[0] + ssq[1] + ssq[2] + ssq[3];

    const float mu  = sum * (1.f / D_MODEL);
    const float var = sq * (1.f / D_MODEL) - mu * mu;
    const float rs  = rsqrtf(var + EPS_LN);
    const float2 w2 = *(const float2*)(w + tid * 2);
    const float2 b2 = *(const float2*)(bias + tid * 2);
    float o0 = (v0 - mu) * rs * w2.x + b2.x;
    float o1 = (v1 - mu) * rs * w2.y + b2.y;
    *(float2*)(Of + (size_t)t * D_MODEL + tid * 2) = make_float2(o0, o1);
    union { __bf16 h2[2]; u16x2 u; } cv;
    cv.h2[0] = (__bf16)o0; cv.h2[1] = (__bf16)o1;
    *(u16x2*)(Oh + (size_t)t * D_MODEL + tid * 2) = cv.u;
}

// ---------------------------------------------------------------------------
// src [s][b][512] -> permuted [b][s][512], fp32 + bf16.  grid = 8192.
// ---------------------------------------------------------------------------
__global__ __launch_bounds__(256) void permute_src(
    const float* __restrict__ src, float* __restrict__ Of, __bf16* __restrict__ Oh)
{
    const int t = blockIdx.x;            // b*512 + s
    const int b = t >> 9, s = t & 511;
    const int tid = threadIdx.x;
    const float2 v = *(const float2*)(src + ((size_t)(s * BATCH + b)) * D_MODEL + tid * 2);
    *(float2*)(Of + (size_t)t * D_MODEL + tid * 2) = v;
    union { __bf16 h2[2]; u16x2 u; } cv;
    cv.h2[0] = (__bf16)v.x; cv.h2[1] = (__bf16)v.y;
    *(u16x2*)(Oh + (size_t)t * D_MODEL + tid * 2) = cv.u;
}

// ---------------------------------------------------------------------------
// Token embedding + posenc -> [b][s][512], fp32 + bf16. One block per row.
// ---------------------------------------------------------------------------
__global__ __launch_bounds__(256) void embed_pos(
    const int* __restrict__ tokens, const float* __restrict__ emb,
    float* __restrict__ Of, __bf16* __restrict__ Oh)
{
    const int t   = blockIdx.x;          // b*128 + s
    const int b   = t >> 7, s = t & 127;
    const int tid = threadIdx.x;
    const int tok = tokens[s * BATCH + b];
    const float C = 9.210340371976184f / 256.f;
    const int d = tid * 2;
    const int j = (d < 256) ? d : (d - 256);
    float a0 = (float)s * expf(-(float)j * C);
    float a1 = (float)s * expf(-(float)(j + 1) * C);
    float pe0 = (d < 256) ? sinf(a0) : cosf(a0);
    float pe1 = (d < 256) ? sinf(a1) : cosf(a1);
    const float2 e2 = *(const float2*)(emb + (size_t)tok * D_MODEL + d);
    float o0 = e2.x + pe0, o1 = e2.y + pe1;
    *(float2*)(Of + (size_t)t * D_MODEL + d) = make_float2(o0, o1);
    union { __bf16 h2[2]; u16x2 u; } cv;
    cv.h2[0] = (__bf16)o0; cv.h2[1] = (__bf16)o1;
    *(u16x2*)(Oh + (size_t)t * D_MODEL + d) = cv.u;
}

// ---------------------------------------------------------------------------
// Multi-segment fp32 -> bf16 (12 segments). Monotonic segment walk.
// ---------------------------------------------------------------------------
struct CvtSeg { const float* s; __bf16* d; int n8; };
struct CvtArgs { CvtSeg seg[12]; int tot8; };

__global__ __launch_bounds__(256) void cvt_multi(CvtArgs a)
{
    const int stride = gridDim.x * 256;
    int sgi = 0;
    int base = 0;
    for (int u = blockIdx.x * 256 + threadIdx.x; u < a.tot8; u += stride) {
        while (u - base >= a.seg[sgi].n8) { base += a.seg[sgi].n8; ++sgi; }
        const int v = u - base;
        const float4 f0 = ((const float4*)a.seg[sgi].s)[v * 2];
        const float4 f1 = ((const float4*)a.seg[sgi].s)[v * 2 + 1];
        union { __bf16 h[8]; u16x8 u; } c;
        c.h[0] = (__bf16)f0.x; c.h[1] = (__bf16)f0.y;
        c.h[2] = (__bf16)f0.z; c.h[3] = (__bf16)f0.w;
        c.h[4] = (__bf16)f1.x; c.h[5] = (__bf16)f1.y;
        c.h[6] = (__bf16)f1.z; c.h[7] = (__bf16)f1.w;
        ((u16x8*)a.seg[sgi].d)[v] = c.u;
    }
}

__global__ __launch_bounds__(256) void pad_outw(
    const float* __restrict__ w, __bf16* __restrict__ o)
{
    const int idx = blockIdx.x * 256 + threadIdx.x;
    const int r = idx >> 9;
    const int c = idx & 511;
    o[idx] = (__bf16)(r < 97 ? w[r * 512 + c] : 0.f);
}

// ---------------------------------------------------------------------------
// Host orchestration
// ---------------------------------------------------------------------------
extern "C" void kernel_launch(void* const* d_in, const int* in_sizes, int n_in,
                              void* d_out, int out_size, void* d_ws, size_t ws_size,
                              hipStream_t stream)
{
    const float* src     = (const float*)d_in[0];
    const int*   tokens  = (const int*)d_in[1];
    const float* tok_emb = (const float*)d_in[2];
    const float* enc_qkv_w = (const float*)d_in[3];
    const float* enc_qkv_b = (const float*)d_in[4];
    const float* enc_out_w = (const float*)d_in[5];
    const float* enc_out_b = (const float*)d_in[6];
    const float* enc_l1_w  = (const float*)d_in[7];
    const float* enc_l1_b  = (const float*)d_in[8];
    const float* enc_l2_w  = (const float*)d_in[9];
    const float* enc_l2_b  = (const float*)d_in[10];
    const float* enc_n1_w  = (const float*)d_in[11];
    const float* enc_n1_b  = (const float*)d_in[12];
    const float* enc_n2_w  = (const float*)d_in[13];
    const float* enc_n2_b  = (const float*)d_in[14];
    const float* dec_qkv_w = (const float*)d_in[15];
    const float* dec_qkv_b = (const float*)d_in[16];
    const float* dec_sout_w = (const float*)d_in[17];
    const float* dec_sout_b = (const float*)d_in[18];
    const float* dec_q_w   = (const float*)d_in[19];
    const float* dec_q_b   = (const float*)d_in[20];
    const float* dec_k_w   = (const float*)d_in[21];
    const float* dec_k_b   = (const float*)d_in[22];
    const float* dec_v_w   = (const float*)d_in[23];
    const float* dec_v_b   = (const float*)d_in[24];
    const float* dec_cout_w = (const float*)d_in[25];
    const float* dec_cout_b = (const float*)d_in[26];
    const float* dec_l1_w  = (const float*)d_in[27];
    const float* dec_l1_b  = (const float*)d_in[28];
    const float* dec_l2_w  = (const float*)d_in[29];
    const float* dec_l2_b  = (const float*)d_in[30];
    const float* dec_n1_w  = (const float*)d_in[31];
    const float* dec_n1_b  = (const float*)d_in[32];
    const float* dec_n2_w  = (const float*)d_in[33];
    const float* dec_n2_b  = (const float*)d_in[34];
    const float* dec_n3_w  = (const float*)d_in[35];
    const float* dec_n3_b  = (const float*)d_in[36];
    const float* out_w     = (const float*)d_in[37];
    const float* out_b     = (const float*)d_in[38];

    const int NE = 512 * BATCH;   // 8192 rows, [b][s]
    const int ND = 128 * BATCH;   // 2048 rows, [b][s]
    const float scale = 0.125f;
    const int BIG = 1 << 30;

    // -------- workspace layout (bytes) --------
    char* w8 = (char*)d_ws;
    float*  Ax_f = (float*) (w8 + 0);          // 16 MB enc residual fp32
    float*  T_f  = (float*) (w8 + 16777216);   //  4 MB dec residual fp32
    __bf16* Ax_h = (__bf16*)(w8 + 20971520);   //  8 MB enc bf16
    __bf16* T_h  = (__bf16*)(w8 + 29360128);   //  2 MB dec bf16
    __bf16* AO_h = (__bf16*)(w8 + 31457280);   //  8 MB attn out bf16
    __bf16* Y_h  = (__bf16*)(w8 + 39845888);   //  8 MB residual-Y bf16
    __bf16* VT   = (__bf16*)(w8 + 48234496);   //  8 MB V-transpose
    __bf16* OWp  = (__bf16*)(w8 + 56623104);   //  0.13 MB padded out_w
    char*   Gb   = w8 + 56754176;              // 33.5 MB union
    __bf16* Gqk  = (__bf16*)Gb;                // qk bf16 [N][1024]
    __bf16* Gh   = (__bf16*)Gb;                // ffn hidden bf16 [N][2048]
    __bf16* Gq   = (__bf16*)Gb;                // cross q bf16 [2048][512]
    __bf16* Gk   = (__bf16*)(Gb + 2097152);    // cross k bf16 [8192][512]
    __bf16* WB   = (__bf16*)(w8 + 90308608);   // weights: 88 MB (upfront) or 9.4 MB

    const bool upfront = ws_size >= (size_t)178388992;

    auto gemmS = [&](const __bf16* Am, const __bf16* Wm, const float* bv,
                     void* C, int N, int M, int K, int relu) {
        const int nb128 = (M / 128) * (N / 128);
        if (nb128 >= 512) {
            dim3 grid(M / 128, N / 128);
            gemm_mfma<128, 1, 1><<<grid, 512, 0, stream>>>(
                Am, Wm, nullptr, BIG, bv, nullptr, 0, C, nullptr, BIG, 0,
                N, M, M, K, relu, 0);
        } else {
            dim3 grid(M / 128, N / 64);
            gemm_mfma<64, 1, 1><<<grid, 512, 0, stream>>>(
                Am, Wm, nullptr, BIG, bv, nullptr, 0, C, nullptr, BIG, 0,
                N, M, M, K, relu, 0);
        }
    };
    auto gemmN = [&](const __bf16* Am, const __bf16* Wm, const __bf16* W2m, int wsplit,
                     const float* bv, const float* bv2, int bsplit,
                     void* C, __bf16* VTp, int m_vt0, int log2S,
                     int N, int M, int MS, int K, bool outbf, int permrow) {
        const int nb128 = ((M + 127) / 128) * (N / 128);
        if (nb128 >= 512) {
            dim3 grid((M + 127) / 128, N / 128);
            if (outbf) gemm_mfma<128, 1, 0><<<grid, 512, 0, stream>>>(
                Am, Wm, W2m, wsplit, bv, bv2, bsplit, C, VTp, m_vt0, log2S,
                N, M, MS, K, 0, permrow);
            else       gemm_mfma<128, 0, 0><<<grid, 512, 0, stream>>>(
                Am, Wm, W2m, wsplit, bv, bv2, bsplit, C, VTp, m_vt0, log2S,
                N, M, MS, K, 0, permrow);
        } else {
            dim3 grid((M + 127) / 128, N / 64);
            if (outbf) gemm_mfma<64, 1, 0><<<grid, 512, 0, stream>>>(
                Am, Wm, W2m, wsplit, bv, bv2, bsplit, C, VTp, m_vt0, log2S,
                N, M, MS, K, 0, permrow);
            else       gemm_mfma<64, 0, 0><<<grid, 512, 0, stream>>>(
                Am, Wm, W2m, wsplit, bv, bv2, bsplit, C, VTp, m_vt0, log2S,
                N, M, MS, K, 0, permrow);
        }
    };
    auto cvt = [&](CvtArgs& a, int blocks) {
        int tot = 0;
        for (int i = 0; i < 12; ++i) tot += a.seg[i].n8;
        a.tot8 = tot;
        cvt_multi<<<blocks, 256, 0, stream>>>(a);
    };

    // ---- upfront: permute src, pad out_w, (mega-)convert weights ----
    permute_src<<<NE, 256, 0, stream>>>(src, Ax_f, Ax_h);
    pad_outw<<<256, 256, 0, stream>>>(out_w, OWp);

    __bf16* WencQKV = WB;
    __bf16* WencOUT = WencQKV + 4718592;
    __bf16* WencL1  = WencOUT + 1572864;
    __bf16* WencL2  = WencL1 + 6291456;
    __bf16* WdecQKV = WencL2 + 6291456;
    __bf16* WdecSOUT = WdecQKV + 4718592;
    __bf16* WdecQ   = WdecSOUT + 1572864;
    __bf16* WdecK   = WdecQ + 1572864;
    __bf16* WdecV   = WdecK + 1572864;
    __bf16* WdecCOUT = WdecV + 1572864;
    __bf16* WdecL1  = WdecCOUT + 1572864;
    __bf16* WdecL2  = WdecL1 + 6291456;

    if (upfront) {
        CvtArgs a = {};
        a.seg[0]  = { enc_qkv_w,  WencQKV,  4718592 / 8 };
        a.seg[1]  = { enc_out_w,  WencOUT,  1572864 / 8 };
        a.seg[2]  = { enc_l1_w,   WencL1,   6291456 / 8 };
        a.seg[3]  = { enc_l2_w,   WencL2,   6291456 / 8 };
        a.seg[4]  = { dec_qkv_w,  WdecQKV,  4718592 / 8 };
        a.seg[5]  = { dec_sout_w, WdecSOUT, 1572864 / 8 };
        a.seg[6]  = { dec_q_w,    WdecQ,    1572864 / 8 };
        a.seg[7]  = { dec_k_w,    WdecK,    1572864 / 8 };
        a.seg[8]  = { dec_v_w,    WdecV,    1572864 / 8 };
        a.seg[9]  = { dec_cout_w, WdecCOUT, 1572864 / 8 };
        a.seg[10] = { dec_l1_w,   WdecL1,   6291456 / 8 };
        a.seg[11] = { dec_l2_w,   WdecL2,   6291456 / 8 };
        cvt(a, 4096);
    }

    // ---------------- Encoder ----------------
    for (int i = 0; i < 6; ++i) {
        __bf16 *wqkv, *wout, *wl1, *wl2;
        if (upfront) {
            wqkv = WencQKV + (size_t)i * 786432;
            wout = WencOUT + (size_t)i * 262144;
            wl1  = WencL1 + (size_t)i * 1048576;
            wl2  = WencL2 + (size_t)i * 1048576;
        } else {
            wqkv = WB; wout = WB + 786432; wl1 = WB + 1048576; wl2 = WB + 2097152;
            CvtArgs a = {};
            a.seg[0] = { enc_qkv_w + (size_t)i * 786432,  wqkv, 786432 / 8 };
            a.seg[1] = { enc_out_w + (size_t)i * 262144,  wout, 262144 / 8 };
            a.seg[2] = { enc_l1_w  + (size_t)i * 1048576, wl1, 1048576 / 8 };
            a.seg[3] = { enc_l2_w  + (size_t)i * 1048576, wl2, 1048576 / 8 };
            cvt(a, 1024);
        }

        // QKV: Q,K -> Gqk (stride 1024), V -> VT directly
        gemmN(Ax_h, wqkv, nullptr, BIG, enc_qkv_b + (size_t)i * 1536, nullptr, 0,
              Gqk, VT, 1024, 9, NE, 1536, 1024, 512, true, 0);
        attn_mfma<0><<<dim3(8, 8, BATCH), 256, 0, stream>>>(
            Gqk, Gqk, VT, AO_h, 512, 512, 1024, 1024, 512, scale);
        gemmS(AO_h, wout, enc_out_b + (size_t)i * 512, Y_h, NE, 512, 512, 0);
        add_ln<<<NE, 256, 0, stream>>>(Ax_f, Y_h,
                                       enc_n1_w + (size_t)i * 512, enc_n1_b + (size_t)i * 512,
                                       Ax_f, Ax_h);
        gemmS(Ax_h, wl1, enc_l1_b + (size_t)i * 2048, Gh, NE, 2048, 512, 1);
        gemmS(Gh, wl2, enc_l2_b + (size_t)i * 512, Y_h, NE, 512, 2048, 0);
        add_ln<<<NE, 256, 0, stream>>>(Ax_f, Y_h,
                                       enc_n2_w + (size_t)i * 512, enc_n2_b + (size_t)i * 512,
                                       Ax_f, Ax_h);
    }

    // ---------------- Decoder ----------------
    embed_pos<<<ND, 256, 0, stream>>>(tokens, tok_emb, T_f, T_h);
    for (int i = 0; i < 6; ++i) {
        __bf16 *dqkv, *dsout, *dq, *dk, *dv, *dcout, *dl1, *dl2;
        if (upfront) {
            dqkv  = WdecQKV + (size_t)i * 786432;
            dsout = WdecSOUT + (size_t)i * 262144;
            dq    = WdecQ + (size_t)i * 262144;
            dk    = WdecK + (size_t)i * 262144;
            dv    = WdecV + (size_t)i * 262144;
            dcout = WdecCOUT + (size_t)i * 262144;
            dl1   = WdecL1 + (size_t)i * 1048576;
            dl2   = WdecL2 + (size_t)i * 1048576;
        } else {
            dqkv = WB; dsout = WB + 786432; dq = WB + 1048576; dk = WB + 1310720;
            dv = WB + 1572864; dcout = WB + 1835008; dl1 = WB + 2097152; dl2 = WB + 3145728;
            CvtArgs a = {};
            a.seg[0] = { dec_qkv_w  + (size_t)i * 786432,  dqkv,  786432 / 8 };
            a.seg[1] = { dec_sout_w + (size_t)i * 262144,  dsout, 262144 / 8 };
            a.seg[2] = { dec_q_w    + (size_t)i * 262144,  dq,    262144 / 8 };
            a.seg[3] = { dec_k_w    + (size_t)i * 262144,  dk,    262144 / 8 };
            a.seg[4] = { dec_v_w    + (size_t)i * 262144,  dv,    262144 / 8 };
            a.seg[5] = { dec_cout_w + (size_t)i * 262144,  dcout, 262144 / 8 };
            a.seg[6] = { dec_l1_w   + (size_t)i * 1048576, dl1,  1048576 / 8 };
            a.seg[7] = { dec_l2_w   + (size_t)i * 1048576, dl2,  1048576 / 8 };
            cvt(a, 1024);
        }

        // causal self-attn: Q,K -> Gqk, V -> VT (S=128)
        gemmN(T_h, dqkv, nullptr, BIG, dec_qkv_b + (size_t)i * 1536, nullptr, 0,
              Gqk, VT, 1024, 7, ND, 1536, 1024, 512, true, 0);
        attn_mfma<1><<<dim3(2, 8, BATCH), 256, 0, stream>>>(
            Gqk, Gqk, VT, AO_h, 128, 128, 1024, 1024, 512, scale);
        gemmS(AO_h, dsout, dec_sout_b + (size_t)i * 512, Y_h, ND, 512, 512, 0);
        add_ln<<<ND, 256, 0, stream>>>(T_f, Y_h,
                                       dec_n1_w + (size_t)i * 512, dec_n1_b + (size_t)i * 512,
                                       T_f, T_h);
        // cross-attn: q -> Gq; merged K|V: K -> Gk, V -> VT (S=512)
        gemmS(T_h, dq, dec_q_b + (size_t)i * 512, Gq, ND, 512, 512, 0);
        gemmN(Ax_h, dk, dv, 512, dec_k_b + (size_t)i * 512, dec_v_b + (size_t)i * 512, 512,
              Gk, VT, 512, 9, NE, 1024, 512, 512, true, 0);
        attn_mfma<0><<<dim3(2, 8, BATCH), 256, 0, stream>>>(
            Gq, Gk, VT, AO_h, 128, 512, 512, 512, 0, scale);
        gemmS(AO_h, dcout, dec_cout_b + (size_t)i * 512, Y_h, ND, 512, 512, 0);
        add_ln<<<ND, 256, 0, stream>>>(T_f, Y_h,
                                       dec_n2_w + (size_t)i * 512, dec_n2_b + (size_t)i * 512,
                                       T_f, T_h);
        // FFN
        gemmS(T_h, dl1, dec_l1_b + (size_t)i * 2048, Gh, ND, 2048, 512, 1);
        gemmS(Gh, dl2, dec_l2_b + (size_t)i * 512, Y_h, ND, 512, 2048, 0);
        add_ln<<<ND, 256, 0, stream>>>(T_f, Y_h,
                                       dec_n3_w + (size_t)i * 512, dec_n3_b + (size_t)i * 512,
                                       T_f, T_h);
    }

    // ---------------- Output projection (rows permuted back to [s][b]) ----
    gemmN(T_h, OWp, nullptr, BIG, out_b, nullptr, 0,
          (float*)d_out, nullptr, BIG, 7, ND, 97, 97, 512, false, 1);
}